// Round 4
// baseline (281.122 us; speedup 1.0000x reference)
//
#include <hip/hip_runtime.h>
#include <math.h>

#define NTOK   4096
#define DMODEL 1024
#define NHEADS 16
#define HDIM   64
#define KDIM   1024

typedef __attribute__((ext_vector_type(8))) short          bf16x8;
typedef __attribute__((ext_vector_type(4))) float          f32x4;
typedef __attribute__((ext_vector_type(16))) float         f32x16;
typedef __attribute__((ext_vector_type(4))) unsigned int   u32x4;
typedef __attribute__((ext_vector_type(4))) unsigned short us4;

static __device__ __forceinline__ unsigned short f2bf(float f) {
    unsigned int u = __float_as_uint(f);
    u += 0x7fffu + ((u >> 16) & 1u);      // round-to-nearest-even
    return (unsigned short)(u >> 16);
}

// pack two floats -> two bf16 in one dword (lo = a, hi = b)
static __device__ __forceinline__ unsigned int pk2bf(float a, float b) {
#if __has_builtin(__builtin_amdgcn_cvt_pk_bf16_f32)
    return __builtin_bit_cast(unsigned int,
                              __builtin_amdgcn_cvt_pk_bf16_f32(a, b));
#else
    unsigned int ua = __float_as_uint(a) + 0x8000u;   // round-half-up
    unsigned int ub = __float_as_uint(b) + 0x8000u;
    return __builtin_amdgcn_perm(ub, ua, 0x07060302u);
#endif
}

#if __has_builtin(__builtin_amdgcn_exp2f)
#define EXP2(x) __builtin_amdgcn_exp2f(x)
#else
#define EXP2(x) exp2f(x)
#endif

// async 16B global -> LDS (wave-uniform LDS base + lane*16)
static __device__ __forceinline__ void async_copy16(void* lds, const void* g) {
    __builtin_amdgcn_global_load_lds(
        (const __attribute__((address_space(1))) unsigned int*)g,
        (__attribute__((address_space(3))) unsigned int*)lds, 16, 0, 0);
}

// combine two unnormalized bf16 partials (packed pairs) with 1/l scale
static __device__ __forceinline__ unsigned int comb2(unsigned int x,
                                                     unsigned int y,
                                                     float inv) {
    float x0 = __uint_as_float(x << 16);
    float x1 = __uint_as_float(x & 0xffff0000u);
    float y0 = __uint_as_float(y << 16);
    float y1 = __uint_as_float(y & 0xffff0000u);
    return pk2bf((x0 + y0) * inv, (x1 + y1) * inv);
}

// ---------------------------------------------------------------------------
// cast + transpose weights: W [k][n] fp32 -> Wt [n][k] bf16. 64x64 LDS tiles.
// ---------------------------------------------------------------------------
__global__ __launch_bounds__(256)
void cast_wt_kernel(const float* __restrict__ Wq, const float* __restrict__ Wk,
                    const float* __restrict__ Wv, const float* __restrict__ Wo,
                    unsigned short* __restrict__ Tq, unsigned short* __restrict__ Tk,
                    unsigned short* __restrict__ Tv, unsigned short* __restrict__ To) {
    __shared__ float Ws[64][65];
    const float* W;
    unsigned short* T;
    switch (blockIdx.z) {
        case 0:  W = Wq; T = Tq; break;
        case 1:  W = Wk; T = Tk; break;
        case 2:  W = Wv; T = Tv; break;
        default: W = Wo; T = To; break;
    }
    const int k0 = blockIdx.x * 64, n0 = blockIdx.y * 64;
    const int t = threadIdx.x;
    #pragma unroll
    for (int i = 0; i < 4; i++) {
        int c  = i * 256 + t;
        int kk = c >> 4;
        int n4 = (c & 15) << 2;
        *(float4*)(&Ws[kk][n4]) =
            *(const float4*)(W + (size_t)(k0 + kk) * DMODEL + n0 + n4);
    }
    __syncthreads();
    #pragma unroll
    for (int i = 0; i < 4; i++) {
        int c  = i * 256 + t;
        int nn = c >> 4;
        int k4 = (c & 15) << 2;
        us4 o = { f2bf(Ws[k4 + 0][nn]), f2bf(Ws[k4 + 1][nn]),
                  f2bf(Ws[k4 + 2][nn]), f2bf(Ws[k4 + 3][nn]) };
        *(us4*)(T + (size_t)(n0 + nn) * KDIM + k0 + k4) = o;
    }
}

// ---------------------------------------------------------------------------
// cast activations fp32 -> bf16, flat row-major. grid (2048, 3).
// ---------------------------------------------------------------------------
__global__ __launch_bounds__(256)
void cast_in_kernel(const float* __restrict__ q, const float* __restrict__ k,
                    const float* __restrict__ v,
                    unsigned short* __restrict__ Qb,
                    unsigned short* __restrict__ Kb,
                    unsigned short* __restrict__ Vb) {
    const float* src;
    unsigned short* dst;
    switch (blockIdx.y) {
        case 0:  src = q; dst = Qb; break;
        case 1:  src = k; dst = Kb; break;
        default: src = v; dst = Vb; break;
    }
    size_t i = ((size_t)blockIdx.x * 256 + threadIdx.x) * 8;
    float4 f0 = *(const float4*)(src + i);
    float4 f1 = *(const float4*)(src + i + 4);
    uint2 o0 = { pk2bf(f0.x, f0.y), pk2bf(f0.z, f0.w) };
    uint2 o1 = { pk2bf(f1.x, f1.y), pk2bf(f1.z, f1.w) };
    *(uint2*)(dst + i)     = o0;
    *(uint2*)(dst + i + 4) = o1;
}

// ---------------------------------------------------------------------------
// QKV GEMM, pre-cast path: C = Ab(bf16)[4096x1024] x Bt(bf16)^T.
// mode 1: [h][tok][d] row-major (Q, K). mode 2: [h][d][tok] (V transposed).
// ---------------------------------------------------------------------------
__global__ __launch_bounds__(256, 3)
void qkv_gemm_pre(const unsigned short* __restrict__ Qb,
                  const unsigned short* __restrict__ Kb,
                  const unsigned short* __restrict__ Vb,
                  const unsigned short* __restrict__ Btq,
                  const unsigned short* __restrict__ Btk,
                  const unsigned short* __restrict__ Btv,
                  unsigned short* __restrict__ Oq, unsigned short* __restrict__ Ok,
                  unsigned short* __restrict__ Ov) {
    __shared__ unsigned short As[128 * 64];
    __shared__ unsigned short Bs[128 * 64];

    const unsigned short* A;
    const unsigned short* Bt;
    unsigned short* Out;
    int mode;
    float sc;
    switch (blockIdx.z) {
        case 0:  A = Qb; Bt = Btq; Out = Oq; mode = 1; sc = 0.18033688011112042f; break;
        case 1:  A = Kb; Bt = Btk; Out = Ok; mode = 1; sc = 1.0f; break;
        default: A = Vb; Bt = Btv; Out = Ov; mode = 2; sc = 1.0f; break;
    }

    const int t    = threadIdx.x;
    const int w    = t >> 6;
    const int lane = t & 63;
    const int quad = lane >> 4;
    const int l15  = lane & 15;
    const int wr   = w >> 1, wc = w & 1;
    const int bm   = blockIdx.y * 128, bn = blockIdx.x * 128;

    f32x4 acc[4][4];
    #pragma unroll
    for (int i = 0; i < 4; i++)
        #pragma unroll
        for (int j = 0; j < 4; j++) acc[i][j] = (f32x4)(0.f);

    for (int k0 = 0; k0 < KDIM; k0 += 64) {
        __syncthreads();
        #pragma unroll
        for (int i = 0; i < 4; i++) {
            int cb = (i * 4 + w) * 64;
            int c  = cb + lane;
            int r  = c >> 3;
            int ko = (c & 7) * 8;
            async_copy16((void*)(Bs + cb * 8),
                         (const void*)(Bt + (size_t)(bn + r) * KDIM + k0 + ko));
            async_copy16((void*)(As + cb * 8),
                         (const void*)(A + (size_t)(bm + r) * KDIM + k0 + ko));
        }
        __syncthreads();
        #pragma unroll
        for (int kq = 0; kq < 2; kq++) {
            bf16x8 af[4], bf[4];
            #pragma unroll
            for (int mt = 0; mt < 4; mt++)
                af[mt] = *(bf16x8*)(As + (wr * 64 + mt * 16 + l15) * 64 + kq * 32 + quad * 8);
            #pragma unroll
            for (int nt = 0; nt < 4; nt++)
                bf[nt] = *(bf16x8*)(Bs + (wc * 64 + nt * 16 + l15) * 64 + kq * 32 + quad * 8);
            #pragma unroll
            for (int mt = 0; mt < 4; mt++)
                #pragma unroll
                for (int nt = 0; nt < 4; nt++)
                    acc[mt][nt] = __builtin_amdgcn_mfma_f32_16x16x32_bf16(
                        af[mt], bf[nt], acc[mt][nt], 0, 0, 0);
        }
    }

    #pragma unroll
    for (int mt = 0; mt < 4; mt++) {
        #pragma unroll
        for (int nt = 0; nt < 4; nt++) {
            int col  = bn + wc * 64 + nt * 16 + l15;
            int row0 = bm + wr * 64 + mt * 16 + quad * 4;
            if (mode == 1) {
                size_t base = ((size_t)(col >> 6)) * NTOK * HDIM + (col & 63);
                #pragma unroll
                for (int r = 0; r < 4; r++)
                    Out[base + (size_t)(row0 + r) * HDIM] = f2bf(acc[mt][nt][r] * sc);
            } else {
                size_t base = ((size_t)(col >> 6)) * HDIM * NTOK +
                              (size_t)(col & 63) * NTOK + row0;
                us4 o = { f2bf(acc[mt][nt][0]), f2bf(acc[mt][nt][1]),
                          f2bf(acc[mt][nt][2]), f2bf(acc[mt][nt][3]) };
                *(us4*)(Out + base) = o;
            }
        }
    }
}

// ---------------------------------------------------------------------------
// QKV GEMM, fallback path (small ws): A fp32 cast in-register.
// ---------------------------------------------------------------------------
__global__ __launch_bounds__(256, 3)
void qkv_gemm(const float* __restrict__ Aq, const float* __restrict__ Ak,
              const float* __restrict__ Av,
              const unsigned short* __restrict__ Btq,
              const unsigned short* __restrict__ Btk,
              const unsigned short* __restrict__ Btv,
              unsigned short* __restrict__ Oq, unsigned short* __restrict__ Ok,
              unsigned short* __restrict__ Ov) {
    __shared__ unsigned short As[128 * 64];
    __shared__ unsigned short Bs[128 * 64];

    const float* A;
    const unsigned short* Bt;
    unsigned short* Out;
    int mode;
    float sc;
    switch (blockIdx.z) {
        case 0:  A = Aq; Bt = Btq; Out = Oq; mode = 1; sc = 0.18033688011112042f; break;
        case 1:  A = Ak; Bt = Btk; Out = Ok; mode = 1; sc = 1.0f; break;
        default: A = Av; Bt = Btv; Out = Ov; mode = 2; sc = 1.0f; break;
    }

    const int t    = threadIdx.x;
    const int w    = t >> 6;
    const int lane = t & 63;
    const int quad = lane >> 4;
    const int l15  = lane & 15;
    const int wr   = w >> 1, wc = w & 1;
    const int bm   = blockIdx.y * 128, bn = blockIdx.x * 128;

    f32x4 acc[4][4];
    #pragma unroll
    for (int i = 0; i < 4; i++)
        #pragma unroll
        for (int j = 0; j < 4; j++) acc[i][j] = (f32x4)(0.f);

    for (int k0 = 0; k0 < KDIM; k0 += 64) {
        __syncthreads();
        #pragma unroll
        for (int i = 0; i < 4; i++) {
            int cb = (i * 4 + w) * 64;
            int c  = cb + lane;
            int r  = c >> 3;
            int ko = (c & 7) * 8;
            async_copy16((void*)(Bs + cb * 8),
                         (const void*)(Bt + (size_t)(bn + r) * KDIM + k0 + ko));
        }
        #pragma unroll
        for (int i = 0; i < 4; i++) {
            int c2 = i * 256 + t;
            int r  = c2 >> 3;
            int k8 = (c2 & 7) * 8;
            const float* src = A + (size_t)(bm + r) * KDIM + k0 + k8;
            float4 f0 = *(const float4*)(src);
            float4 f1 = *(const float4*)(src + 4);
            uint2 p0 = { pk2bf(f0.x, f0.y), pk2bf(f0.z, f0.w) };
            uint2 p1 = { pk2bf(f1.x, f1.y), pk2bf(f1.z, f1.w) };
            *(uint2*)(As + r * 64 + k8)     = p0;
            *(uint2*)(As + r * 64 + k8 + 4) = p1;
        }
        __syncthreads();
        #pragma unroll
        for (int kq = 0; kq < 2; kq++) {
            bf16x8 af[4], bf[4];
            #pragma unroll
            for (int mt = 0; mt < 4; mt++)
                af[mt] = *(bf16x8*)(As + (wr * 64 + mt * 16 + l15) * 64 + kq * 32 + quad * 8);
            #pragma unroll
            for (int nt = 0; nt < 4; nt++)
                bf[nt] = *(bf16x8*)(Bs + (wc * 64 + nt * 16 + l15) * 64 + kq * 32 + quad * 8);
            #pragma unroll
            for (int mt = 0; mt < 4; mt++)
                #pragma unroll
                for (int nt = 0; nt < 4; nt++)
                    acc[mt][nt] = __builtin_amdgcn_mfma_f32_16x16x32_bf16(
                        af[mt], bf[nt], acc[mt][nt], 0, 0, 0);
        }
    }

    #pragma unroll
    for (int mt = 0; mt < 4; mt++) {
        #pragma unroll
        for (int nt = 0; nt < 4; nt++) {
            int col  = bn + wc * 64 + nt * 16 + l15;
            int row0 = bm + wr * 64 + mt * 16 + quad * 4;
            if (mode == 1) {
                size_t base = ((size_t)(col >> 6)) * NTOK * HDIM + (col & 63);
                #pragma unroll
                for (int r = 0; r < 4; r++)
                    Out[base + (size_t)(row0 + r) * HDIM] = f2bf(acc[mt][nt][r] * sc);
            } else {
                size_t base = ((size_t)(col >> 6)) * HDIM * NTOK +
                              (size_t)(col & 63) * NTOK + row0;
                us4 o = { f2bf(acc[mt][nt][0]), f2bf(acc[mt][nt][1]),
                          f2bf(acc[mt][nt][2]), f2bf(acc[mt][nt][3]) };
                *(us4*)(Out + base) = o;
            }
        }
    }
}

// ---------------------------------------------------------------------------
// Output GEMM (fallback): out(fp32) = ctx(bf16) x WoT(bf16)^T. 64x128 tile.
// ---------------------------------------------------------------------------
__global__ __launch_bounds__(256, 3)
void out_gemm(const unsigned short* __restrict__ A,
              const unsigned short* __restrict__ Bt,
              float* __restrict__ Out) {
    __shared__ unsigned short As[64 * 64];
    __shared__ unsigned short Bs[128 * 64];

    const int t    = threadIdx.x;
    const int w    = t >> 6;
    const int lane = t & 63;
    const int quad = lane >> 4;
    const int l15  = lane & 15;
    const int wr   = w >> 1, wc = w & 1;
    const int bm   = blockIdx.y * 64, bn = blockIdx.x * 128;

    f32x4 acc[2][4];
    #pragma unroll
    for (int i = 0; i < 2; i++)
        #pragma unroll
        for (int j = 0; j < 4; j++) acc[i][j] = (f32x4)(0.f);

    for (int k0 = 0; k0 < KDIM; k0 += 64) {
        __syncthreads();
        #pragma unroll
        for (int i = 0; i < 4; i++) {
            int cb = (i * 4 + w) * 64;
            int c  = cb + lane;
            int r  = c >> 3;
            int ko = (c & 7) * 8;
            async_copy16((void*)(Bs + cb * 8),
                         (const void*)(Bt + (size_t)(bn + r) * KDIM + k0 + ko));
        }
        #pragma unroll
        for (int i = 0; i < 2; i++) {
            int cb = (i * 4 + w) * 64;
            int c  = cb + lane;
            int r  = c >> 3;
            int ko = (c & 7) * 8;
            async_copy16((void*)(As + cb * 8),
                         (const void*)(A + (size_t)(bm + r) * KDIM + k0 + ko));
        }
        __syncthreads();
        #pragma unroll
        for (int kq = 0; kq < 2; kq++) {
            bf16x8 af[2], bf[4];
            #pragma unroll
            for (int mt = 0; mt < 2; mt++)
                af[mt] = *(bf16x8*)(As + (wr * 32 + mt * 16 + l15) * 64 + kq * 32 + quad * 8);
            #pragma unroll
            for (int nt = 0; nt < 4; nt++)
                bf[nt] = *(bf16x8*)(Bs + (wc * 64 + nt * 16 + l15) * 64 + kq * 32 + quad * 8);
            #pragma unroll
            for (int mt = 0; mt < 2; mt++)
                #pragma unroll
                for (int nt = 0; nt < 4; nt++)
                    acc[mt][nt] = __builtin_amdgcn_mfma_f32_16x16x32_bf16(
                        af[mt], bf[nt], acc[mt][nt], 0, 0, 0);
        }
    }

    #pragma unroll
    for (int mt = 0; mt < 2; mt++) {
        #pragma unroll
        for (int nt = 0; nt < 4; nt++) {
            int col  = bn + wc * 64 + nt * 16 + l15;
            int row0 = bm + wr * 32 + mt * 16 + quad * 4;
            #pragma unroll
            for (int r = 0; r < 4; r++)
                Out[(size_t)(row0 + r) * DMODEL + col] = acc[mt][nt][r];
        }
    }
}

// ---------------------------------------------------------------------------
// Output GEMM + fused split-K combine: A-tile = (POa + POb) / (la + lb),
// combined in-register while staging into LDS (replaces combine_kernel).
// ---------------------------------------------------------------------------
__global__ __launch_bounds__(256, 3)
void out_gemm_comb(const unsigned short* __restrict__ POa,
                   const float* __restrict__ lbuf,
                   const unsigned short* __restrict__ Bt,
                   float* __restrict__ Out) {
    __shared__ unsigned short As[64 * 64];
    __shared__ unsigned short Bs[128 * 64];

    const unsigned short* POb = POa + (size_t)NTOK * DMODEL;

    const int t    = threadIdx.x;
    const int w    = t >> 6;
    const int lane = t & 63;
    const int quad = lane >> 4;
    const int l15  = lane & 15;
    const int wr   = w >> 1, wc = w & 1;
    const int bm   = blockIdx.y * 64, bn = blockIdx.x * 128;

    f32x4 acc[2][4];
    #pragma unroll
    for (int i = 0; i < 2; i++)
        #pragma unroll
        for (int j = 0; j < 4; j++) acc[i][j] = (f32x4)(0.f);

    for (int k0 = 0; k0 < KDIM; k0 += 64) {
        __syncthreads();
        #pragma unroll
        for (int i = 0; i < 4; i++) {
            int cb = (i * 4 + w) * 64;
            int c  = cb + lane;
            int r  = c >> 3;
            int ko = (c & 7) * 8;
            async_copy16((void*)(Bs + cb * 8),
                         (const void*)(Bt + (size_t)(bn + r) * KDIM + k0 + ko));
        }
        // A-tile: load both PO halves, combine with 1/(la+lb), ds_write bf16
        #pragma unroll
        for (int i = 0; i < 2; i++) {
            int c   = i * 256 + t;        // 0..511
            int r   = c >> 3;             // row 0..63
            int k8  = (c & 7) * 8;        // col offset 0..56
            size_t row = (size_t)(bm + r);
            int col = k0 + k8;
            int hh  = col >> 6;
            uint4 a = *(const uint4*)(POa + row * DMODEL + col);
            uint4 b = *(const uint4*)(POb + row * DMODEL + col);
            float la = lbuf[(size_t)hh * NTOK + row];
            float lb = lbuf[(size_t)NHEADS * NTOK + (size_t)hh * NTOK + row];
            float inv = 1.f / (la + lb);
            uint4 o = { comb2(a.x, b.x, inv), comb2(a.y, b.y, inv),
                        comb2(a.z, b.z, inv), comb2(a.w, b.w, inv) };
            *(uint4*)(As + r * 64 + k8) = o;
        }
        __syncthreads();
        #pragma unroll
        for (int kq = 0; kq < 2; kq++) {
            bf16x8 af[2], bf[4];
            #pragma unroll
            for (int mt = 0; mt < 2; mt++)
                af[mt] = *(bf16x8*)(As + (wr * 32 + mt * 16 + l15) * 64 + kq * 32 + quad * 8);
            #pragma unroll
            for (int nt = 0; nt < 4; nt++)
                bf[nt] = *(bf16x8*)(Bs + (wc * 64 + nt * 16 + l15) * 64 + kq * 32 + quad * 8);
            #pragma unroll
            for (int mt = 0; mt < 2; mt++)
                #pragma unroll
                for (int nt = 0; nt < 4; nt++)
                    acc[mt][nt] = __builtin_amdgcn_mfma_f32_16x16x32_bf16(
                        af[mt], bf[nt], acc[mt][nt], 0, 0, 0);
        }
    }

    #pragma unroll
    for (int mt = 0; mt < 2; mt++) {
        #pragma unroll
        for (int nt = 0; nt < 4; nt++) {
            int col  = bn + wc * 64 + nt * 16 + l15;
            int row0 = bm + wr * 32 + mt * 16 + quad * 4;
            #pragma unroll
            for (int r = 0; r < 4; r++)
                Out[(size_t)(row0 + r) * DMODEL + col] = acc[mt][nt][r];
        }
    }
}

// ---------------------------------------------------------------------------
// Flash attention SPLIT-K, 32x32x16 MFMA + in-register P.
// GEOMETRY CHANGE vs validated round-1 kernel (layouts/math identical):
// 2-wave blocks (64 q rows), 32-key tiles, 16 KB LDS, 8 blocks/CU ->
// 8 independent barrier domains per CU (desync -> MFMA/VALU overlap).
// K LDS tile [key 32][d 64] rows 128B, XOR-chunk ^(key&7) (as validated).
// V LDS tile [d 64][key 32] rows 64B, XOR-chunk ^(d&3) (rederived, uniform).
// ---------------------------------------------------------------------------
__global__ __launch_bounds__(128, 4)
void attn_split(const unsigned short* __restrict__ Q,
                const unsigned short* __restrict__ K,
                const unsigned short* __restrict__ Vt,
                unsigned short* __restrict__ PO,   // [half][row][h*64+d] bf16
                float* __restrict__ lbuf) {        // [half][h][row] fp32
    __shared__ __align__(16) unsigned short Ks[2 * 2048]; // [buf][key 32][d 64]
    __shared__ __align__(16) unsigned short Vs[2 * 2048]; // [buf][d 64][key 32]

    const int qt   = blockIdx.x;       // 64 q rows
    const int h    = blockIdx.y;
    const int half = blockIdx.z;       // keys [half*2048, half*2048+2048)
    const int t    = threadIdx.x;      // 0..127
    const int w    = t >> 6;
    const int lane = t & 63;
    const int r    = lane & 31;        // q-col (B) / key- or d-row (A)
    const int hi   = lane >> 5;
    const int xh8  = (r & 7) ^ hi;     // K frag XOR key
    const int xh4  = (r & 3) ^ hi;     // V frag XOR key

    // Q fragments (B operand): lane holds Q[qrow][ds*16 + 8*hi + j]
    const unsigned short* Qg =
        Q + ((size_t)h * NTOK + qt * 64 + w * 32 + r) * HDIM + hi * 8;
    bf16x8 qf[4];
    #pragma unroll
    for (int ds = 0; ds < 4; ds++)
        qf[ds] = *(const bf16x8*)(Qg + ds * 16);

    const unsigned short* Kg = K  + ((size_t)h * NTOK + half * 2048) * HDIM;
    const unsigned short* Vg = Vt + (size_t)h * HDIM * NTOK + half * 2048;

    // staging sources (hoisted), XOR-chunk swizzled:
    // K: thread covers key-row krow = t>>3 (plus +16 in copy B), chunk t&7
    const int krow = t >> 3;
    const int koo  = ((t & 7) ^ (krow & 7)) * 8;
    const unsigned short* kbase = Kg + (size_t)krow * HDIM + koo;
    // V: thread covers d-row vrow = t>>2 (plus +32 in copy B), chunk t&3
    const int vrow = t >> 2;
    const int voo  = ((t & 3) ^ (vrow & 3)) * 8;
    const unsigned short* vbase = Vg + (size_t)vrow * NTOK + voo;

    unsigned short* ksd = Ks + w * 512;   // wave-uniform LDS dest (1KB/wave)
    unsigned short* vsd = Vs + w * 512;

    auto stage = [&](int kt, int b) {
        const unsigned short* kp = kbase + (size_t)kt * 32 * HDIM;
        const unsigned short* vp = vbase + kt * 32;
        async_copy16((void*)(ksd + b * 2048),        (const void*)kp);
        async_copy16((void*)(ksd + b * 2048 + 1024), (const void*)(kp + 16 * HDIM));
        async_copy16((void*)(vsd + b * 2048),        (const void*)vp);
        async_copy16((void*)(vsd + b * 2048 + 1024), (const void*)(vp + (size_t)32 * NTOK));
    };

    f32x16 O0 = (f32x16)(0.f), O1 = (f32x16)(0.f);
    float l0 = 0.f, l1 = 0.f, l2 = 0.f, l3 = 0.f;

    stage(0, 0);

    for (int kt = 0; kt < 64; kt++) {
        const int cur = kt & 1;
        __syncthreads();                    // drains vmcnt -> buf[cur] ready
        if (kt + 1 < 64) stage(kt + 1, cur ^ 1);

        const unsigned short* Kb = Ks + cur * 2048 + r * 64;  // key-row r
        const unsigned short* Vb = Vs + cur * 2048 + r * 32;  // d-row r

        // ---- S^T = K Q^T : 32 keys, K-dim 64 = 4 slices ----
        f32x16 S = (f32x16)(0.f);
        #pragma unroll
        for (int ds = 0; ds < 4; ds++) {
            bf16x8 kf = *(const bf16x8*)(Kb + ((2 * ds) ^ xh8) * 8);
            S = __builtin_amdgcn_mfma_f32_32x32x16_bf16(kf, qf[ds], S, 0, 0, 0);
        }

        // ---- per 16-key group: exp2 -> pack -> permlane swap -> PV ----
        #pragma unroll
        for (int kg = 0; kg < 2; kg++) {
            float p0 = EXP2(S[kg * 8 + 0]);
            float p1 = EXP2(S[kg * 8 + 1]);
            float p2 = EXP2(S[kg * 8 + 2]);
            float p3 = EXP2(S[kg * 8 + 3]);
            float p4 = EXP2(S[kg * 8 + 4]);
            float p5 = EXP2(S[kg * 8 + 5]);
            float p6 = EXP2(S[kg * 8 + 6]);
            float p7 = EXP2(S[kg * 8 + 7]);
            l0 += p0; l1 += p1; l2 += p2; l3 += p3;
            l0 += p4; l1 += p5; l2 += p6; l3 += p7;
            unsigned int w0 = pk2bf(p0, p1);
            unsigned int w2 = pk2bf(p4, p5);
            unsigned int w1 = pk2bf(p2, p3);
            unsigned int w3 = pk2bf(p6, p7);
            asm volatile("v_permlane32_swap_b32 %0, %1" : "+v"(w0), "+v"(w2));
            asm volatile("v_permlane32_swap_b32 %0, %1" : "+v"(w1), "+v"(w3));
            u32x4 pw = { w0, w1, w2, w3 };
            bf16x8 pf = __builtin_bit_cast(bf16x8, pw);
            int cv = ((2 * kg) ^ xh4) * 8;
            bf16x8 v0 = *(const bf16x8*)(Vb + cv);          // d 0..31
            bf16x8 v1 = *(const bf16x8*)(Vb + 1024 + cv);   // d 32..63
            O0 = __builtin_amdgcn_mfma_f32_32x32x16_bf16(v0, pf, O0, 0, 0, 0);
            O1 = __builtin_amdgcn_mfma_f32_32x32x16_bf16(v1, pf, O1, 0, 0, 0);
        }
    }

    // ---- epilogue: unnormalized partial O (bf16) + l (fp32) ----
    float lt   = (l0 + l1) + (l2 + l3);
    float ltot = lt + __shfl_xor(lt, 32, 64);

    unsigned short* POh = PO + (size_t)half * NTOK * DMODEL;
    size_t row = (size_t)qt * 64 + w * 32 + r;
    unsigned short* dst = POh + row * DMODEL + h * HDIM;
    #pragma unroll
    for (int db = 0; db < 2; db++) {
        const f32x16 O = db ? O1 : O0;
        #pragma unroll
        for (int g = 0; g < 4; g++) {
            int d = db * 32 + g * 8 + hi * 4;   // C row = (reg&3)+8*(reg>>2)+4*hi
            uint2 o = { pk2bf(O[g * 4 + 0], O[g * 4 + 1]),
                        pk2bf(O[g * 4 + 2], O[g * 4 + 3]) };
            *(uint2*)(dst + d) = o;
        }
    }
    if (hi == 0)
        lbuf[((size_t)half * NHEADS + h) * NTOK + row] = ltot;
}

// ---------------------------------------------------------------------------
// Fallback single-pass attention (small ws), Ps-based (validated).
// ---------------------------------------------------------------------------
__global__ __launch_bounds__(256)
void attn_mfma(const unsigned short* __restrict__ Q,
               const unsigned short* __restrict__ K,
               const unsigned short* __restrict__ Vt,
               unsigned short* __restrict__ ctx) {
    __shared__ __align__(16) unsigned short Ks[2 * 4096];
    __shared__ __align__(16) unsigned short Vs[2 * 4096];
    __shared__ __align__(16) unsigned short Ps[4][32][72];

    const int h    = blockIdx.y;
    const int qt   = blockIdx.x;
    const int t    = threadIdx.x;
    const int w    = t >> 6;
    const int lane = t & 63;
    const int quad = lane >> 4;
    const int l15  = lane & 15;

    const unsigned short* Qg =
        Q + ((size_t)h * NTOK + qt * 128 + w * 32 + l15) * HDIM;
    bf16x8 qf[2][2];
    qf[0][0] = *(const bf16x8*)(Qg + quad * 8);
    qf[0][1] = *(const bf16x8*)(Qg + 32 + quad * 8);
    qf[1][0] = *(const bf16x8*)(Qg + 16 * HDIM + quad * 8);
    qf[1][1] = *(const bf16x8*)(Qg + 16 * HDIM + 32 + quad * 8);

    const unsigned short* Kg = K  + (size_t)h * NTOK * HDIM;
    const unsigned short* Vg = Vt + (size_t)h * HDIM * NTOK;

    const int rr = t >> 3;
    const int oo = ((t & 7) ^ (rr & 7)) * 8;
    const unsigned short* kbase = Kg + (size_t)rr * HDIM + oo;
    const unsigned short* vbase = Vg + (size_t)rr * NTOK + oo;
    unsigned short* ksd = Ks + w * 512;
    unsigned short* vsd = Vs + w * 512;

    auto stage = [&](int kt, int b) {
        const unsigned short* kp = kbase + (size_t)kt * 64 * HDIM;
        const unsigned short* vp = vbase + kt * 64;
        async_copy16((void*)(ksd + b * 4096),        (const void*)kp);
        async_copy16((void*)(ksd + b * 4096 + 2048), (const void*)(kp + 32 * HDIM));
        async_copy16((void*)(vsd + b * 4096),        (const void*)vp);
        async_copy16((void*)(vsd + b * 4096 + 2048), (const void*)(vp + (size_t)32 * NTOK));
    };

    const int xb = l15 & 7;
    const int a0 = l15 * 64 + ((quad    ) ^ xb) * 8;
    const int a1 = l15 * 64 + ((quad + 4) ^ xb) * 8;

    const bf16x8 ones = { 16256, 16256, 16256, 16256,
                          16256, 16256, 16256, 16256 };

    f32x4 O[2][4];
    f32x4 lacc[2];
    #pragma unroll
    for (int tl = 0; tl < 2; tl++) {
        lacc[tl] = (f32x4)(0.f);
        #pragma unroll
        for (int dt = 0; dt < 4; dt++) O[tl][dt] = (f32x4)(0.f);
    }

    stage(0, 0);

    for (int kt = 0; kt < NTOK / 64; kt++) {
        const int cur = kt & 1;
        __syncthreads();
        if (kt + 1 < NTOK / 64) stage(kt + 1, cur ^ 1);

        f32x4 s[2][4];
        #pragma unroll
        for (int kc = 0; kc < 4; kc++) {
            bf16x8 kf0 = *(bf16x8*)(Ks + cur * 4096 + kc * 1024 + a0);
            bf16x8 kf1 = *(bf16x8*)(Ks + cur * 4096 + kc * 1024 + a1);
            #pragma unroll
            for (int tl = 0; tl < 2; tl++) {
                f32x4 acc = (f32x4)(0.f);
                acc = __builtin_amdgcn_mfma_f32_16x16x32_bf16(kf0, qf[tl][0], acc, 0, 0, 0);
                acc = __builtin_amdgcn_mfma_f32_16x16x32_bf16(kf1, qf[tl][1], acc, 0, 0, 0);
                s[tl][kc] = acc;
            }
        }

        bf16x8 vf[4][2];
        #pragma unroll
        for (int dt = 0; dt < 4; dt++) {
            vf[dt][0] = *(bf16x8*)(Vs + cur * 4096 + dt * 1024 + a0);
            vf[dt][1] = *(bf16x8*)(Vs + cur * 4096 + dt * 1024 + a1);
        }

        #pragma unroll
        for (int tl = 0; tl < 2; tl++) {
            #pragma unroll
            for (int kc = 0; kc < 4; kc++) {
                float e0 = EXP2(s[tl][kc][0]);
                float e1 = EXP2(s[tl][kc][1]);
                float e2 = EXP2(s[tl][kc][2]);
                float e3 = EXP2(s[tl][kc][3]);
                uint2 p = { pk2bf(e0, e1), pk2bf(e2, e3) };
                *(uint2*)(&Ps[w][tl * 16 + l15][kc * 16 + quad * 4]) = p;
            }
            asm volatile("s_waitcnt lgkmcnt(0)" ::: "memory");

            bf16x8 pf0 = *(bf16x8*)(&Ps[w][tl * 16 + l15][quad * 8]);
            bf16x8 pf1 = *(bf16x8*)(&Ps[w][tl * 16 + l15][32 + quad * 8]);
            lacc[tl] = __builtin_amdgcn_mfma_f32_16x16x32_bf16(ones, pf0, lacc[tl], 0, 0, 0);
            lacc[tl] = __builtin_amdgcn_mfma_f32_16x16x32_bf16(ones, pf1, lacc[tl], 0, 0, 0);
            #pragma unroll
            for (int dt = 0; dt < 4; dt++) {
                O[tl][dt] = __builtin_amdgcn_mfma_f32_16x16x32_bf16(vf[dt][0], pf0, O[tl][dt], 0, 0, 0);
                O[tl][dt] = __builtin_amdgcn_mfma_f32_16x16x32_bf16(vf[dt][1], pf1, O[tl][dt], 0, 0, 0);
            }
        }
    }

    #pragma unroll
    for (int tl = 0; tl < 2; tl++) {
        float inv = 1.f / lacc[tl][0];
        size_t row = (size_t)qt * 128 + w * 32 + tl * 16 + l15;
        #pragma unroll
        for (int dt = 0; dt < 4; dt++) {
            uint2 o = { pk2bf(O[tl][dt][0] * inv, O[tl][dt][1] * inv),
                        pk2bf(O[tl][dt][2] * inv, O[tl][dt][3] * inv) };
            *(uint2*)(ctx + row * DMODEL + h * HDIM + dt * 16 + quad * 4) = o;
        }
    }
}

// ---------------------------------------------------------------------------
extern "C" void kernel_launch(void* const* d_in, const int* in_sizes, int n_in,
                              void* d_out, int out_size, void* d_ws, size_t ws_size,
                              hipStream_t stream) {
    const float* q  = (const float*)d_in[0];
    const float* k  = (const float*)d_in[1];
    const float* v  = (const float*)d_in[2];
    const float* Wq = (const float*)d_in[3];
    const float* Wk = (const float*)d_in[4];
    const float* Wv = (const float*)d_in[5];
    const float* Wo = (const float*)d_in[6];
    float* out = (float*)d_out;

    // ws: weights 8MB | Qh,Kh,Vth 24MB | ctx 8MB | scratch 24MB
    // scratch = Qb/Kb/Vb during projections, then PO(16MB)+lbuf(0.5MB) in attn.
    unsigned short* WqT = (unsigned short*)d_ws;
    unsigned short* WkT = WqT + (size_t)DMODEL * KDIM;
    unsigned short* WvT = WkT + (size_t)DMODEL * KDIM;
    unsigned short* WoT = WvT + (size_t)DMODEL * KDIM;
    unsigned short* Qh  = WoT + (size_t)DMODEL * KDIM;
    unsigned short* Kh  = Qh  + (size_t)NTOK * DMODEL;
    unsigned short* Vth = Kh  + (size_t)NTOK * DMODEL;
    unsigned short* ctx = Vth + (size_t)NTOK * DMODEL;
    unsigned short* Qb  = ctx + (size_t)NTOK * DMODEL;
    unsigned short* Kb  = Qb  + (size_t)NTOK * DMODEL;
    unsigned short* Vb  = Kb  + (size_t)NTOK * DMODEL;
    unsigned short* PO  = Qb;                                // overlay (Qb dead)
    float*          lb  = (float*)(PO + (size_t)2 * NTOK * DMODEL);

    const bool bigws = ws_size >= (size_t)67108864;   // 64 MB

    cast_wt_kernel<<<dim3(16, 16, 4), 256, 0, stream>>>(Wq, Wk, Wv, Wo,
                                                        WqT, WkT, WvT, WoT);
    if (bigws) {
        cast_in_kernel<<<dim3(2048, 3), 256, 0, stream>>>(q, k, v, Qb, Kb, Vb);
        qkv_gemm_pre<<<dim3(DMODEL / 128, NTOK / 128, 3), 256, 0, stream>>>(
            Qb, Kb, Vb, WqT, WkT, WvT, Qh, Kh, Vth);
        attn_split<<<dim3(NTOK / 64, NHEADS, 2), 128, 0, stream>>>(
            Qh, Kh, Vth, PO, lb);
        out_gemm_comb<<<dim3(DMODEL / 128, NTOK / 64), 256, 0, stream>>>(
            PO, lb, WoT, out);
    } else {
        qkv_gemm<<<dim3(DMODEL / 128, NTOK / 128, 3), 256, 0, stream>>>(
            q, k, v, WqT, WkT, WvT, Qh, Kh, Vth);
        attn_mfma<<<dim3(NTOK / 128, NHEADS), 256, 0, stream>>>(Qh, Kh, Vth, ctx);
        out_gemm<<<dim3(DMODEL / 128, NTOK / 64), 256, 0, stream>>>(ctx, WoT, out);
    }
}

// Round 6
// 258.368 us; speedup vs baseline: 1.0881x; 1.0881x over previous
//
#include <hip/hip_runtime.h>
#include <math.h>

#define NTOK   4096
#define DMODEL 1024
#define NHEADS 16
#define HDIM   64
#define KDIM   1024

typedef __attribute__((ext_vector_type(8))) short          bf16x8;
typedef __attribute__((ext_vector_type(4))) float          f32x4;
typedef __attribute__((ext_vector_type(16))) float         f32x16;
typedef __attribute__((ext_vector_type(4))) unsigned int   u32x4;
typedef __attribute__((ext_vector_type(4))) unsigned short us4;

static __device__ __forceinline__ unsigned short f2bf(float f) {
    unsigned int u = __float_as_uint(f);
    u += 0x7fffu + ((u >> 16) & 1u);      // round-to-nearest-even
    return (unsigned short)(u >> 16);
}

// pack two floats -> two bf16 in one dword (lo = a, hi = b)
static __device__ __forceinline__ unsigned int pk2bf(float a, float b) {
#if __has_builtin(__builtin_amdgcn_cvt_pk_bf16_f32)
    return __builtin_bit_cast(unsigned int,
                              __builtin_amdgcn_cvt_pk_bf16_f32(a, b));
#else
    unsigned int ua = __float_as_uint(a) + 0x8000u;   // round-half-up
    unsigned int ub = __float_as_uint(b) + 0x8000u;
    return __builtin_amdgcn_perm(ub, ua, 0x07060302u);
#endif
}

#if __has_builtin(__builtin_amdgcn_exp2f)
#define EXP2(x) __builtin_amdgcn_exp2f(x)
#else
#define EXP2(x) exp2f(x)
#endif

// async 16B global -> LDS (wave-uniform LDS base + lane*16)
static __device__ __forceinline__ void async_copy16(void* lds, const void* g) {
    __builtin_amdgcn_global_load_lds(
        (const __attribute__((address_space(1))) unsigned int*)g,
        (__attribute__((address_space(3))) unsigned int*)lds, 16, 0, 0);
}

// combine two unnormalized bf16 partials (packed pairs) with 1/l scale
static __device__ __forceinline__ unsigned int comb2(unsigned int x,
                                                     unsigned int y,
                                                     float inv) {
    float x0 = __uint_as_float(x << 16);
    float x1 = __uint_as_float(x & 0xffff0000u);
    float y0 = __uint_as_float(y << 16);
    float y1 = __uint_as_float(y & 0xffff0000u);
    return pk2bf((x0 + y0) * inv, (x1 + y1) * inv);
}

// ---------------------------------------------------------------------------
// QKV GEMM epilogues through padded LDS (stride 136 shorts = 272 B:
// 16B-aligned b128 reads, write phase ~2-way banks = free), then fully
// coalesced 16B global stores. Numerics identical to the direct-scatter
// epilogue (same f2bf, same scale application point).
// Cs pool = 17408 shorts (34.8 KB); As/Bs alias the first 16384.
// ---------------------------------------------------------------------------
#define CS_LD 136

// row-major output [h][tok][d] (Q scaled, K): Cs[row][col]
static __device__ __forceinline__ void epi_rowmajor(
        unsigned short* Cs, unsigned short* Out, const f32x4 (&acc)[4][4],
        float sc, int wr, int wc, int quad, int l15, int t, int bm, int bn) {
    __syncthreads();                       // all waves done reading As/Bs
    #pragma unroll
    for (int mt = 0; mt < 4; mt++)
        #pragma unroll
        for (int nt = 0; nt < 4; nt++) {
            int col = wc * 64 + nt * 16 + l15;
            int row = wr * 64 + mt * 16 + quad * 4;
            #pragma unroll
            for (int r = 0; r < 4; r++)
                Cs[(row + r) * CS_LD + col] = f2bf(acc[mt][nt][r] * sc);
        }
    __syncthreads();
    #pragma unroll
    for (int p = 0; p < 8; p++) {
        int idx = p * 2048 + t * 8;
        int rl = idx >> 7, cl = idx & 127;     // rl = tok, cl = n
        uint4 v = *(const uint4*)(Cs + rl * CS_LD + cl);
        int n = bn + cl;
        *(uint4*)(Out + (size_t)(n >> 6) * NTOK * HDIM
                      + (size_t)(bm + rl) * HDIM + (n & 63)) = v;
    }
}

// transposed output [h][d][tok] (V): Cs[col][row], us4 writes (4 consec tok)
static __device__ __forceinline__ void epi_transposed(
        unsigned short* Cs, unsigned short* Out, const f32x4 (&acc)[4][4],
        int wr, int wc, int quad, int l15, int t, int bm, int bn) {
    __syncthreads();
    #pragma unroll
    for (int mt = 0; mt < 4; mt++)
        #pragma unroll
        for (int nt = 0; nt < 4; nt++) {
            int col = wc * 64 + nt * 16 + l15;
            int row = wr * 64 + mt * 16 + quad * 4;
            us4 o = { f2bf(acc[mt][nt][0]), f2bf(acc[mt][nt][1]),
                      f2bf(acc[mt][nt][2]), f2bf(acc[mt][nt][3]) };
            *(us4*)(Cs + col * CS_LD + row) = o;
        }
    __syncthreads();
    #pragma unroll
    for (int p = 0; p < 8; p++) {
        int idx = p * 2048 + t * 8;
        int cl = idx >> 7, rl = idx & 127;     // cl = n (d), rl = tok
        uint4 v = *(const uint4*)(Cs + cl * CS_LD + rl);
        int n = bn + cl;
        *(uint4*)(Out + (size_t)(n >> 6) * HDIM * NTOK
                      + (size_t)(n & 63) * NTOK + (bm + rl)) = v;
    }
}

// ---------------------------------------------------------------------------
// cast + transpose weights: W [k][n] fp32 -> Wt [n][k] bf16. 64x64 LDS tiles.
// ---------------------------------------------------------------------------
__global__ __launch_bounds__(256)
void cast_wt_kernel(const float* __restrict__ Wq, const float* __restrict__ Wk,
                    const float* __restrict__ Wv, const float* __restrict__ Wo,
                    unsigned short* __restrict__ Tq, unsigned short* __restrict__ Tk,
                    unsigned short* __restrict__ Tv, unsigned short* __restrict__ To) {
    __shared__ float Ws[64][65];
    const float* W;
    unsigned short* T;
    switch (blockIdx.z) {
        case 0:  W = Wq; T = Tq; break;
        case 1:  W = Wk; T = Tk; break;
        case 2:  W = Wv; T = Tv; break;
        default: W = Wo; T = To; break;
    }
    const int k0 = blockIdx.x * 64, n0 = blockIdx.y * 64;
    const int t = threadIdx.x;
    #pragma unroll
    for (int i = 0; i < 4; i++) {
        int c  = i * 256 + t;
        int kk = c >> 4;
        int n4 = (c & 15) << 2;
        *(float4*)(&Ws[kk][n4]) =
            *(const float4*)(W + (size_t)(k0 + kk) * DMODEL + n0 + n4);
    }
    __syncthreads();
    #pragma unroll
    for (int i = 0; i < 4; i++) {
        int c  = i * 256 + t;
        int nn = c >> 4;
        int k4 = (c & 15) << 2;
        us4 o = { f2bf(Ws[k4 + 0][nn]), f2bf(Ws[k4 + 1][nn]),
                  f2bf(Ws[k4 + 2][nn]), f2bf(Ws[k4 + 3][nn]) };
        *(us4*)(T + (size_t)(n0 + nn) * KDIM + k0 + k4) = o;
    }
}

// ---------------------------------------------------------------------------
// cast activations fp32 -> bf16, flat row-major. grid (2048, 3).
// ---------------------------------------------------------------------------
__global__ __launch_bounds__(256)
void cast_in_kernel(const float* __restrict__ q, const float* __restrict__ k,
                    const float* __restrict__ v,
                    unsigned short* __restrict__ Qb,
                    unsigned short* __restrict__ Kb,
                    unsigned short* __restrict__ Vb) {
    const float* src;
    unsigned short* dst;
    switch (blockIdx.y) {
        case 0:  src = q; dst = Qb; break;
        case 1:  src = k; dst = Kb; break;
        default: src = v; dst = Vb; break;
    }
    size_t i = ((size_t)blockIdx.x * 256 + threadIdx.x) * 8;
    float4 f0 = *(const float4*)(src + i);
    float4 f1 = *(const float4*)(src + i + 4);
    uint2 o0 = { pk2bf(f0.x, f0.y), pk2bf(f0.z, f0.w) };
    uint2 o1 = { pk2bf(f1.x, f1.y), pk2bf(f1.z, f1.w) };
    *(uint2*)(dst + i)     = o0;
    *(uint2*)(dst + i + 4) = o1;
}

// ---------------------------------------------------------------------------
// QKV GEMM, pre-cast path: C = Ab(bf16)[4096x1024] x Bt(bf16)^T.
// mode 1: [h][tok][d] row-major (Q scaled, K). mode 2: [h][d][tok] (V).
// Epilogue via LDS tile -> coalesced 16B stores (this round's change).
// ---------------------------------------------------------------------------
__global__ __launch_bounds__(256, 3)
void qkv_gemm_pre(const unsigned short* __restrict__ Qb,
                  const unsigned short* __restrict__ Kb,
                  const unsigned short* __restrict__ Vb,
                  const unsigned short* __restrict__ Btq,
                  const unsigned short* __restrict__ Btk,
                  const unsigned short* __restrict__ Btv,
                  unsigned short* __restrict__ Oq, unsigned short* __restrict__ Ok,
                  unsigned short* __restrict__ Ov) {
    __shared__ __align__(16) unsigned short Sm[17408];
    unsigned short* As = Sm;
    unsigned short* Bs = Sm + 8192;

    const unsigned short* A;
    const unsigned short* Bt;
    unsigned short* Out;
    int mode;
    float sc;
    switch (blockIdx.z) {
        case 0:  A = Qb; Bt = Btq; Out = Oq; mode = 1; sc = 0.18033688011112042f; break;
        case 1:  A = Kb; Bt = Btk; Out = Ok; mode = 1; sc = 1.0f; break;
        default: A = Vb; Bt = Btv; Out = Ov; mode = 2; sc = 1.0f; break;
    }

    const int t    = threadIdx.x;
    const int w    = t >> 6;
    const int lane = t & 63;
    const int quad = lane >> 4;
    const int l15  = lane & 15;
    const int wr   = w >> 1, wc = w & 1;
    const int bm   = blockIdx.y * 128, bn = blockIdx.x * 128;

    f32x4 acc[4][4];
    #pragma unroll
    for (int i = 0; i < 4; i++)
        #pragma unroll
        for (int j = 0; j < 4; j++) acc[i][j] = (f32x4)(0.f);

    for (int k0 = 0; k0 < KDIM; k0 += 64) {
        __syncthreads();
        #pragma unroll
        for (int i = 0; i < 4; i++) {
            int cb = (i * 4 + w) * 64;
            int c  = cb + lane;
            int r  = c >> 3;
            int ko = (c & 7) * 8;
            async_copy16((void*)(Bs + cb * 8),
                         (const void*)(Bt + (size_t)(bn + r) * KDIM + k0 + ko));
            async_copy16((void*)(As + cb * 8),
                         (const void*)(A + (size_t)(bm + r) * KDIM + k0 + ko));
        }
        __syncthreads();
        #pragma unroll
        for (int kq = 0; kq < 2; kq++) {
            bf16x8 af[4], bf[4];
            #pragma unroll
            for (int mt = 0; mt < 4; mt++)
                af[mt] = *(bf16x8*)(As + (wr * 64 + mt * 16 + l15) * 64 + kq * 32 + quad * 8);
            #pragma unroll
            for (int nt = 0; nt < 4; nt++)
                bf[nt] = *(bf16x8*)(Bs + (wc * 64 + nt * 16 + l15) * 64 + kq * 32 + quad * 8);
            #pragma unroll
            for (int mt = 0; mt < 4; mt++)
                #pragma unroll
                for (int nt = 0; nt < 4; nt++)
                    acc[mt][nt] = __builtin_amdgcn_mfma_f32_16x16x32_bf16(
                        af[mt], bf[nt], acc[mt][nt], 0, 0, 0);
        }
    }

    if (mode == 1)
        epi_rowmajor(Sm, Out, acc, sc, wr, wc, quad, l15, t, bm, bn);
    else
        epi_transposed(Sm, Out, acc, wr, wc, quad, l15, t, bm, bn);
}

// ---------------------------------------------------------------------------
// QKV GEMM, fallback path (small ws): A fp32 cast in-register.
// ---------------------------------------------------------------------------
__global__ __launch_bounds__(256, 3)
void qkv_gemm(const float* __restrict__ Aq, const float* __restrict__ Ak,
              const float* __restrict__ Av,
              const unsigned short* __restrict__ Btq,
              const unsigned short* __restrict__ Btk,
              const unsigned short* __restrict__ Btv,
              unsigned short* __restrict__ Oq, unsigned short* __restrict__ Ok,
              unsigned short* __restrict__ Ov) {
    __shared__ __align__(16) unsigned short Sm[17408];
    unsigned short* As = Sm;
    unsigned short* Bs = Sm + 8192;

    const float* A;
    const unsigned short* Bt;
    unsigned short* Out;
    int mode;
    float sc;
    switch (blockIdx.z) {
        case 0:  A = Aq; Bt = Btq; Out = Oq; mode = 1; sc = 0.18033688011112042f; break;
        case 1:  A = Ak; Bt = Btk; Out = Ok; mode = 1; sc = 1.0f; break;
        default: A = Av; Bt = Btv; Out = Ov; mode = 2; sc = 1.0f; break;
    }

    const int t    = threadIdx.x;
    const int w    = t >> 6;
    const int lane = t & 63;
    const int quad = lane >> 4;
    const int l15  = lane & 15;
    const int wr   = w >> 1, wc = w & 1;
    const int bm   = blockIdx.y * 128, bn = blockIdx.x * 128;

    f32x4 acc[4][4];
    #pragma unroll
    for (int i = 0; i < 4; i++)
        #pragma unroll
        for (int j = 0; j < 4; j++) acc[i][j] = (f32x4)(0.f);

    for (int k0 = 0; k0 < KDIM; k0 += 64) {
        __syncthreads();
        #pragma unroll
        for (int i = 0; i < 4; i++) {
            int cb = (i * 4 + w) * 64;
            int c  = cb + lane;
            int r  = c >> 3;
            int ko = (c & 7) * 8;
            async_copy16((void*)(Bs + cb * 8),
                         (const void*)(Bt + (size_t)(bn + r) * KDIM + k0 + ko));
        }
        #pragma unroll
        for (int i = 0; i < 4; i++) {
            int c2 = i * 256 + t;
            int r  = c2 >> 3;
            int k8 = (c2 & 7) * 8;
            const float* src = A + (size_t)(bm + r) * KDIM + k0 + k8;
            float4 f0 = *(const float4*)(src);
            float4 f1 = *(const float4*)(src + 4);
            uint2 p0 = { pk2bf(f0.x, f0.y), pk2bf(f0.z, f0.w) };
            uint2 p1 = { pk2bf(f1.x, f1.y), pk2bf(f1.z, f1.w) };
            *(uint2*)(As + r * 64 + k8)     = p0;
            *(uint2*)(As + r * 64 + k8 + 4) = p1;
        }
        __syncthreads();
        #pragma unroll
        for (int kq = 0; kq < 2; kq++) {
            bf16x8 af[4], bf[4];
            #pragma unroll
            for (int mt = 0; mt < 4; mt++)
                af[mt] = *(bf16x8*)(As + (wr * 64 + mt * 16 + l15) * 64 + kq * 32 + quad * 8);
            #pragma unroll
            for (int nt = 0; nt < 4; nt++)
                bf[nt] = *(bf16x8*)(Bs + (wc * 64 + nt * 16 + l15) * 64 + kq * 32 + quad * 8);
            #pragma unroll
            for (int mt = 0; mt < 4; mt++)
                #pragma unroll
                for (int nt = 0; nt < 4; nt++)
                    acc[mt][nt] = __builtin_amdgcn_mfma_f32_16x16x32_bf16(
                        af[mt], bf[nt], acc[mt][nt], 0, 0, 0);
        }
    }

    if (mode == 1)
        epi_rowmajor(Sm, Out, acc, sc, wr, wc, quad, l15, t, bm, bn);
    else
        epi_transposed(Sm, Out, acc, wr, wc, quad, l15, t, bm, bn);
}

// ---------------------------------------------------------------------------
// Output GEMM (fallback): out(fp32) = ctx(bf16) x WoT(bf16)^T. 64x128 tile.
// ---------------------------------------------------------------------------
__global__ __launch_bounds__(256, 3)
void out_gemm(const unsigned short* __restrict__ A,
              const unsigned short* __restrict__ Bt,
              float* __restrict__ Out) {
    __shared__ unsigned short As[64 * 64];
    __shared__ unsigned short Bs[128 * 64];

    const int t    = threadIdx.x;
    const int w    = t >> 6;
    const int lane = t & 63;
    const int quad = lane >> 4;
    const int l15  = lane & 15;
    const int wr   = w >> 1, wc = w & 1;
    const int bm   = blockIdx.y * 64, bn = blockIdx.x * 128;

    f32x4 acc[2][4];
    #pragma unroll
    for (int i = 0; i < 2; i++)
        #pragma unroll
        for (int j = 0; j < 4; j++) acc[i][j] = (f32x4)(0.f);

    for (int k0 = 0; k0 < KDIM; k0 += 64) {
        __syncthreads();
        #pragma unroll
        for (int i = 0; i < 4; i++) {
            int cb = (i * 4 + w) * 64;
            int c  = cb + lane;
            int r  = c >> 3;
            int ko = (c & 7) * 8;
            async_copy16((void*)(Bs + cb * 8),
                         (const void*)(Bt + (size_t)(bn + r) * KDIM + k0 + ko));
        }
        #pragma unroll
        for (int i = 0; i < 2; i++) {
            int cb = (i * 4 + w) * 64;
            int c  = cb + lane;
            int r  = c >> 3;
            int ko = (c & 7) * 8;
            async_copy16((void*)(As + cb * 8),
                         (const void*)(A + (size_t)(bm + r) * KDIM + k0 + ko));
        }
        __syncthreads();
        #pragma unroll
        for (int kq = 0; kq < 2; kq++) {
            bf16x8 af[2], bf[4];
            #pragma unroll
            for (int mt = 0; mt < 2; mt++)
                af[mt] = *(bf16x8*)(As + (wr * 32 + mt * 16 + l15) * 64 + kq * 32 + quad * 8);
            #pragma unroll
            for (int nt = 0; nt < 4; nt++)
                bf[nt] = *(bf16x8*)(Bs + (wc * 64 + nt * 16 + l15) * 64 + kq * 32 + quad * 8);
            #pragma unroll
            for (int mt = 0; mt < 2; mt++)
                #pragma unroll
                for (int nt = 0; nt < 4; nt++)
                    acc[mt][nt] = __builtin_amdgcn_mfma_f32_16x16x32_bf16(
                        af[mt], bf[nt], acc[mt][nt], 0, 0, 0);
        }
    }

    #pragma unroll
    for (int mt = 0; mt < 2; mt++) {
        #pragma unroll
        for (int nt = 0; nt < 4; nt++) {
            int col  = bn + wc * 64 + nt * 16 + l15;
            int row0 = bm + wr * 32 + mt * 16 + quad * 4;
            #pragma unroll
            for (int r = 0; r < 4; r++)
                Out[(size_t)(row0 + r) * DMODEL + col] = acc[mt][nt][r];
        }
    }
}

// ---------------------------------------------------------------------------
// Output GEMM + fused split-K combine: A-tile = (POa + POb) / (la + lb),
// combined in-register while staging into LDS (replaces combine_kernel).
// ---------------------------------------------------------------------------
__global__ __launch_bounds__(256, 3)
void out_gemm_comb(const unsigned short* __restrict__ POa,
                   const float* __restrict__ lbuf,
                   const unsigned short* __restrict__ Bt,
                   float* __restrict__ Out) {
    __shared__ unsigned short As[64 * 64];
    __shared__ unsigned short Bs[128 * 64];

    const unsigned short* POb = POa + (size_t)NTOK * DMODEL;

    const int t    = threadIdx.x;
    const int w    = t >> 6;
    const int lane = t & 63;
    const int quad = lane >> 4;
    const int l15  = lane & 15;
    const int wr   = w >> 1, wc = w & 1;
    const int bm   = blockIdx.y * 64, bn = blockIdx.x * 128;

    f32x4 acc[2][4];
    #pragma unroll
    for (int i = 0; i < 2; i++)
        #pragma unroll
        for (int j = 0; j < 4; j++) acc[i][j] = (f32x4)(0.f);

    for (int k0 = 0; k0 < KDIM; k0 += 64) {
        __syncthreads();
        #pragma unroll
        for (int i = 0; i < 4; i++) {
            int cb = (i * 4 + w) * 64;
            int c  = cb + lane;
            int r  = c >> 3;
            int ko = (c & 7) * 8;
            async_copy16((void*)(Bs + cb * 8),
                         (const void*)(Bt + (size_t)(bn + r) * KDIM + k0 + ko));
        }
        // A-tile: load both PO halves, combine with 1/(la+lb), ds_write bf16
        #pragma unroll
        for (int i = 0; i < 2; i++) {
            int c   = i * 256 + t;        // 0..511
            int r   = c >> 3;             // row 0..63
            int k8  = (c & 7) * 8;        // col offset 0..56
            size_t row = (size_t)(bm + r);
            int col = k0 + k8;
            int hh  = col >> 6;
            uint4 a = *(const uint4*)(POa + row * DMODEL + col);
            uint4 b = *(const uint4*)(POb + row * DMODEL + col);
            float la = lbuf[(size_t)hh * NTOK + row];
            float lb = lbuf[(size_t)NHEADS * NTOK + (size_t)hh * NTOK + row];
            float inv = 1.f / (la + lb);
            uint4 o = { comb2(a.x, b.x, inv), comb2(a.y, b.y, inv),
                        comb2(a.z, b.z, inv), comb2(a.w, b.w, inv) };
            *(uint4*)(As + r * 64 + k8) = o;
        }
        __syncthreads();
        #pragma unroll
        for (int kq = 0; kq < 2; kq++) {
            bf16x8 af[2], bf[4];
            #pragma unroll
            for (int mt = 0; mt < 2; mt++)
                af[mt] = *(bf16x8*)(As + (wr * 32 + mt * 16 + l15) * 64 + kq * 32 + quad * 8);
            #pragma unroll
            for (int nt = 0; nt < 4; nt++)
                bf[nt] = *(bf16x8*)(Bs + (wc * 64 + nt * 16 + l15) * 64 + kq * 32 + quad * 8);
            #pragma unroll
            for (int mt = 0; mt < 2; mt++)
                #pragma unroll
                for (int nt = 0; nt < 4; nt++)
                    acc[mt][nt] = __builtin_amdgcn_mfma_f32_16x16x32_bf16(
                        af[mt], bf[nt], acc[mt][nt], 0, 0, 0);
        }
    }

    #pragma unroll
    for (int mt = 0; mt < 2; mt++) {
        #pragma unroll
        for (int nt = 0; nt < 4; nt++) {
            int col  = bn + wc * 64 + nt * 16 + l15;
            int row0 = bm + wr * 32 + mt * 16 + quad * 4;
            #pragma unroll
            for (int r = 0; r < 4; r++)
                Out[(size_t)(row0 + r) * DMODEL + col] = acc[mt][nt][r];
        }
    }
}

// ---------------------------------------------------------------------------
// Flash attention SPLIT-K, 32x32x16 MFMA + in-register P (validated round-1).
// block = (head, 128 q-rows, key-half of 2048). 4 waves x 32 q-rows.
// S^T = mfma(K, Q): lane(col q = lane&31, hi = lane>>5) holds 16 keys
//   key = (reg&3) + 8*(reg>>2) + 4*hi.
// P -> PV B-frag via cvt_pk pairs + v_permlane32_swap.
// l via 4 independent VALU add chains. Double-buffered K/V (32 KB LDS),
// one barrier per K-tile, prefetch in flight across the compute phase.
// ---------------------------------------------------------------------------
__global__ __launch_bounds__(256, 4)
void attn_split(const unsigned short* __restrict__ Q,
                const unsigned short* __restrict__ K,
                const unsigned short* __restrict__ Vt,
                unsigned short* __restrict__ PO,   // [half][row][h*64+d] bf16
                float* __restrict__ lbuf) {        // [half][h][row] fp32
    __shared__ __align__(16) unsigned short Ks[2 * 4096]; // [buf][key 64][d 64] XOR-chunked
    __shared__ __align__(16) unsigned short Vs[2 * 4096]; // [buf][d 64][key 64] XOR-chunked

    const int qt   = blockIdx.x;       // 128 q rows
    const int h    = blockIdx.y;
    const int half = blockIdx.z;       // keys [half*2048, half*2048+2048)
    const int t    = threadIdx.x;
    const int w    = t >> 6;
    const int lane = t & 63;
    const int r    = lane & 31;        // q-col (B) / key- or d-row (A)
    const int hi   = lane >> 5;
    const int xh   = (r & 7) ^ hi;     // XOR-chunk key for frag reads

    // Q fragments (B operand): lane holds Q[qrow][ds*16 + 8*hi + j]
    const unsigned short* Qg =
        Q + ((size_t)h * NTOK + qt * 128 + w * 32 + r) * HDIM + hi * 8;
    bf16x8 qf[4];
    #pragma unroll
    for (int ds = 0; ds < 4; ds++)
        qf[ds] = *(const bf16x8*)(Qg + ds * 16);

    const unsigned short* Kg = K  + ((size_t)h * NTOK + half * 2048) * HDIM;
    const unsigned short* Vg = Vt + (size_t)h * HDIM * NTOK + half * 2048;

    // staging source (hoisted): thread covers row rr, XOR-swizzled chunk
    const int rr = t >> 3;
    const int oo = ((t & 7) ^ (rr & 7)) * 8;
    const unsigned short* kbase = Kg + (size_t)rr * HDIM + oo;
    const unsigned short* vbase = Vg + (size_t)rr * NTOK + oo;
    unsigned short* ksd = Ks + w * 512;   // wave-uniform LDS dest
    unsigned short* vsd = Vs + w * 512;

    auto stage = [&](int kt, int b) {
        const unsigned short* kp = kbase + (size_t)kt * 64 * HDIM;
        const unsigned short* vp = vbase + kt * 64;
        async_copy16((void*)(ksd + b * 4096),        (const void*)kp);
        async_copy16((void*)(ksd + b * 4096 + 2048), (const void*)(kp + 32 * HDIM));
        async_copy16((void*)(vsd + b * 4096),        (const void*)vp);
        async_copy16((void*)(vsd + b * 4096 + 2048), (const void*)(vp + (size_t)32 * NTOK));
    };

    f32x16 O0 = (f32x16)(0.f), O1 = (f32x16)(0.f);
    float l0 = 0.f, l1 = 0.f, l2 = 0.f, l3 = 0.f;

    stage(0, 0);

    for (int kt = 0; kt < 32; kt++) {
        const int cur = kt & 1;
        __syncthreads();                    // drains vmcnt for buf[cur]
        if (kt + 1 < 32) stage(kt + 1, cur ^ 1);

        const unsigned short* Kb = Ks + cur * 4096 + r * 64;
        const unsigned short* Vb = Vs + cur * 4096 + r * 64;

        // ---- S^T = K Q^T : two 32-key blocks, K-dim 64 = 4 slices ----
        f32x16 S0 = (f32x16)(0.f), S1 = (f32x16)(0.f);
        #pragma unroll
        for (int ds = 0; ds < 4; ds++) {
            int c = ((2 * ds) ^ xh) * 8;
            bf16x8 k0 = *(const bf16x8*)(Kb + c);
            bf16x8 k1 = *(const bf16x8*)(Kb + 2048 + c);
            S0 = __builtin_amdgcn_mfma_f32_32x32x16_bf16(k0, qf[ds], S0, 0, 0, 0);
            S1 = __builtin_amdgcn_mfma_f32_32x32x16_bf16(k1, qf[ds], S1, 0, 0, 0);
        }

        // ---- per key-block: exp2 -> pack -> permlane swap -> PV ----
        #pragma unroll
        for (int kb = 0; kb < 2; kb++) {
            const f32x16 S = kb ? S1 : S0;
            float p[16];
            #pragma unroll
            for (int i = 0; i < 16; i++) p[i] = EXP2(S[i]);
            // l accumulation: 4 independent chains
            #pragma unroll
            for (int i = 0; i < 4; i++) {
                l0 += p[i * 4 + 0];
                l1 += p[i * 4 + 1];
                l2 += p[i * 4 + 2];
                l3 += p[i * 4 + 3];
            }
            #pragma unroll
            for (int g = 0; g < 2; g++) {   // 16-key group within block
                unsigned int w0 = pk2bf(p[g * 8 + 0], p[g * 8 + 1]);
                unsigned int w2 = pk2bf(p[g * 8 + 4], p[g * 8 + 5]);
                unsigned int w1 = pk2bf(p[g * 8 + 2], p[g * 8 + 3]);
                unsigned int w3 = pk2bf(p[g * 8 + 6], p[g * 8 + 7]);
                asm volatile("v_permlane32_swap_b32 %0, %1" : "+v"(w0), "+v"(w2));
                asm volatile("v_permlane32_swap_b32 %0, %1" : "+v"(w1), "+v"(w3));
                u32x4 pw = { w0, w1, w2, w3 };
                bf16x8 pf = __builtin_bit_cast(bf16x8, pw);
                int kg = kb * 2 + g;
                int c  = ((2 * kg) ^ xh) * 8;
                bf16x8 v0 = *(const bf16x8*)(Vb + c);
                bf16x8 v1 = *(const bf16x8*)(Vb + 2048 + c);
                O0 = __builtin_amdgcn_mfma_f32_32x32x16_bf16(v0, pf, O0, 0, 0, 0);
                O1 = __builtin_amdgcn_mfma_f32_32x32x16_bf16(v1, pf, O1, 0, 0, 0);
            }
        }
    }

    // ---- epilogue: unnormalized partial O (bf16) + l (fp32) ----
    float lt  = (l0 + l1) + (l2 + l3);
    float ltot = lt + __shfl_xor(lt, 32, 64);

    unsigned short* POh = PO + (size_t)half * NTOK * DMODEL;
    size_t row = (size_t)qt * 128 + w * 32 + r;
    unsigned short* dst = POh + row * DMODEL + h * HDIM;
    #pragma unroll
    for (int db = 0; db < 2; db++) {
        const f32x16 O = db ? O1 : O0;
        #pragma unroll
        for (int g = 0; g < 4; g++) {
            int d = db * 32 + g * 8 + hi * 4;   // C row = (reg&3)+8*(reg>>2)+4*hi
            uint2 o = { pk2bf(O[g * 4 + 0], O[g * 4 + 1]),
                        pk2bf(O[g * 4 + 2], O[g * 4 + 3]) };
            *(uint2*)(dst + d) = o;
        }
    }
    if (hi == 0)
        lbuf[((size_t)half * NHEADS + h) * NTOK + row] = ltot;
}

// ---------------------------------------------------------------------------
// Fallback single-pass attention (small ws), Ps-based (validated).
// ---------------------------------------------------------------------------
__global__ __launch_bounds__(256)
void attn_mfma(const unsigned short* __restrict__ Q,
               const unsigned short* __restrict__ K,
               const unsigned short* __restrict__ Vt,
               unsigned short* __restrict__ ctx) {
    __shared__ __align__(16) unsigned short Ks[2 * 4096];
    __shared__ __align__(16) unsigned short Vs[2 * 4096];
    __shared__ __align__(16) unsigned short Ps[4][32][72];

    const int h    = blockIdx.y;
    const int qt   = blockIdx.x;
    const int t    = threadIdx.x;
    const int w    = t >> 6;
    const int lane = t & 63;
    const int quad = lane >> 4;
    const int l15  = lane & 15;

    const unsigned short* Qg =
        Q + ((size_t)h * NTOK + qt * 128 + w * 32 + l15) * HDIM;
    bf16x8 qf[2][2];
    qf[0][0] = *(const bf16x8*)(Qg + quad * 8);
    qf[0][1] = *(const bf16x8*)(Qg + 32 + quad * 8);
    qf[1][0] = *(const bf16x8*)(Qg + 16 * HDIM + quad * 8);
    qf[1][1] = *(const bf16x8*)(Qg + 16 * HDIM + 32 + quad * 8);

    const unsigned short* Kg = K  + (size_t)h * NTOK * HDIM;
    const unsigned short* Vg = Vt + (size_t)h * HDIM * NTOK;

    const int rr = t >> 3;
    const int oo = ((t & 7) ^ (rr & 7)) * 8;
    const unsigned short* kbase = Kg + (size_t)rr * HDIM + oo;
    const unsigned short* vbase = Vg + (size_t)rr * NTOK + oo;
    unsigned short* ksd = Ks + w * 512;
    unsigned short* vsd = Vs + w * 512;

    auto stage = [&](int kt, int b) {
        const unsigned short* kp = kbase + (size_t)kt * 64 * HDIM;
        const unsigned short* vp = vbase + kt * 64;
        async_copy16((void*)(ksd + b * 4096),        (const void*)kp);
        async_copy16((void*)(ksd + b * 4096 + 2048), (const void*)(kp + 32 * HDIM));
        async_copy16((void*)(vsd + b * 4096),        (const void*)vp);
        async_copy16((void*)(vsd + b * 4096 + 2048), (const void*)(vp + (size_t)32 * NTOK));
    };

    const int xb = l15 & 7;
    const int a0 = l15 * 64 + ((quad    ) ^ xb) * 8;
    const int a1 = l15 * 64 + ((quad + 4) ^ xb) * 8;

    const bf16x8 ones = { 16256, 16256, 16256, 16256,
                          16256, 16256, 16256, 16256 };

    f32x4 O[2][4];
    f32x4 lacc[2];
    #pragma unroll
    for (int tl = 0; tl < 2; tl++) {
        lacc[tl] = (f32x4)(0.f);
        #pragma unroll
        for (int dt = 0; dt < 4; dt++) O[tl][dt] = (f32x4)(0.f);
    }

    stage(0, 0);

    for (int kt = 0; kt < NTOK / 64; kt++) {
        const int cur = kt & 1;
        __syncthreads();
        if (kt + 1 < NTOK / 64) stage(kt + 1, cur ^ 1);

        f32x4 s[2][4];
        #pragma unroll
        for (int kc = 0; kc < 4; kc++) {
            bf16x8 kf0 = *(bf16x8*)(Ks + cur * 4096 + kc * 1024 + a0);
            bf16x8 kf1 = *(bf16x8*)(Ks + cur * 4096 + kc * 1024 + a1);
            #pragma unroll
            for (int tl = 0; tl < 2; tl++) {
                f32x4 acc = (f32x4)(0.f);
                acc = __builtin_amdgcn_mfma_f32_16x16x32_bf16(kf0, qf[tl][0], acc, 0, 0, 0);
                acc = __builtin_amdgcn_mfma_f32_16x16x32_bf16(kf1, qf[tl][1], acc, 0, 0, 0);
                s[tl][kc] = acc;
            }
        }

        bf16x8 vf[4][2];
        #pragma unroll
        for (int dt = 0; dt < 4; dt++) {
            vf[dt][0] = *(bf16x8*)(Vs + cur * 4096 + dt * 1024 + a0);
            vf[dt][1] = *(bf16x8*)(Vs + cur * 4096 + dt * 1024 + a1);
        }

        #pragma unroll
        for (int tl = 0; tl < 2; tl++) {
            #pragma unroll
            for (int kc = 0; kc < 4; kc++) {
                float e0 = EXP2(s[tl][kc][0]);
                float e1 = EXP2(s[tl][kc][1]);
                float e2 = EXP2(s[tl][kc][2]);
                float e3 = EXP2(s[tl][kc][3]);
                uint2 p = { pk2bf(e0, e1), pk2bf(e2, e3) };
                *(uint2*)(&Ps[w][tl * 16 + l15][kc * 16 + quad * 4]) = p;
            }
            asm volatile("s_waitcnt lgkmcnt(0)" ::: "memory");

            bf16x8 pf0 = *(bf16x8*)(&Ps[w][tl * 16 + l15][quad * 8]);
            bf16x8 pf1 = *(bf16x8*)(&Ps[w][tl * 16 + l15][32 + quad * 8]);
            lacc[tl] = __builtin_amdgcn_mfma_f32_16x16x32_bf16(ones, pf0, lacc[tl], 0, 0, 0);
            lacc[tl] = __builtin_amdgcn_mfma_f32_16x16x32_bf16(ones, pf1, lacc[tl], 0, 0, 0);
            #pragma unroll
            for (int dt = 0; dt < 4; dt++) {
                O[tl][dt] = __builtin_amdgcn_mfma_f32_16x16x32_bf16(vf[dt][0], pf0, O[tl][dt], 0, 0, 0);
                O[tl][dt] = __builtin_amdgcn_mfma_f32_16x16x32_bf16(vf[dt][1], pf1, O[tl][dt], 0, 0, 0);
            }
        }
    }

    #pragma unroll
    for (int tl = 0; tl < 2; tl++) {
        float inv = 1.f / lacc[tl][0];
        size_t row = (size_t)qt * 128 + w * 32 + tl * 16 + l15;
        #pragma unroll
        for (int dt = 0; dt < 4; dt++) {
            uint2 o = { pk2bf(O[tl][dt][0] * inv, O[tl][dt][1] * inv),
                        pk2bf(O[tl][dt][2] * inv, O[tl][dt][3] * inv) };
            *(uint2*)(ctx + row * DMODEL + h * HDIM + dt * 16 + quad * 4) = o;
        }
    }
}

// ---------------------------------------------------------------------------
extern "C" void kernel_launch(void* const* d_in, const int* in_sizes, int n_in,
                              void* d_out, int out_size, void* d_ws, size_t ws_size,
                              hipStream_t stream) {
    const float* q  = (const float*)d_in[0];
    const float* k  = (const float*)d_in[1];
    const float* v  = (const float*)d_in[2];
    const float* Wq = (const float*)d_in[3];
    const float* Wk = (const float*)d_in[4];
    const float* Wv = (const float*)d_in[5];
    const float* Wo = (const float*)d_in[6];
    float* out = (float*)d_out;

    // ws: weights 8MB | Qh,Kh,Vth 24MB | ctx 8MB | scratch 24MB
    // scratch = Qb/Kb/Vb during projections, then PO(16MB)+lbuf(0.5MB) in attn.
    unsigned short* WqT = (unsigned short*)d_ws;
    unsigned short* WkT = WqT + (size_t)DMODEL * KDIM;
    unsigned short* WvT = WkT + (size_t)DMODEL * KDIM;
    unsigned short* WoT = WvT + (size_t)DMODEL * KDIM;
    unsigned short* Qh  = WoT + (size_t)DMODEL * KDIM;   // [h][tok][d]
    unsigned short* Kh  = Qh  + (size_t)NTOK * DMODEL;   // [h][tok][d]
    unsigned short* Vth = Kh  + (size_t)NTOK * DMODEL;   // [h][d][tok]
    unsigned short* ctx = Vth + (size_t)NTOK * DMODEL;
    unsigned short* Qb  = ctx + (size_t)NTOK * DMODEL;
    unsigned short* Kb  = Qb  + (size_t)NTOK * DMODEL;
    unsigned short* Vb  = Kb  + (size_t)NTOK * DMODEL;
    unsigned short* PO  = Qb;                                // overlay (Qb dead)
    float*          lb  = (float*)(PO + (size_t)2 * NTOK * DMODEL);

    const bool bigws = ws_size >= (size_t)67108864;   // 64 MB

    cast_wt_kernel<<<dim3(16, 16, 4), 256, 0, stream>>>(Wq, Wk, Wv, Wo,
                                                        WqT, WkT, WvT, WoT);
    if (bigws) {
        cast_in_kernel<<<dim3(2048, 3), 256, 0, stream>>>(q, k, v, Qb, Kb, Vb);
        qkv_gemm_pre<<<dim3(DMODEL / 128, NTOK / 128, 3), 256, 0, stream>>>(
            Qb, Kb, Vb, WqT, WkT, WvT, Qh, Kh, Vth);
        attn_split<<<dim3(NTOK / 128, NHEADS, 2), 256, 0, stream>>>(
            Qh, Kh, Vth, PO, lb);
        out_gemm_comb<<<dim3(DMODEL / 128, NTOK / 64), 256, 0, stream>>>(
            PO, lb, WoT, out);
    } else {
        qkv_gemm<<<dim3(DMODEL / 128, NTOK / 128, 3), 256, 0, stream>>>(
            q, k, v, WqT, WkT, WvT, Qh, Kh, Vth);
        attn_mfma<<<dim3(NTOK / 128, NHEADS), 256, 0, stream>>>(Qh, Kh, Vth, ctx);
        out_gemm<<<dim3(DMODEL / 128, NTOK / 64), 256, 0, stream>>>(ctx, WoT, out);
    }
}

// Round 7
// 253.292 us; speedup vs baseline: 1.1099x; 1.0200x over previous
//
#include <hip/hip_runtime.h>
#include <math.h>

#define NTOK   4096
#define DMODEL 1024
#define NHEADS 16
#define HDIM   64
#define KDIM   1024

typedef __attribute__((ext_vector_type(8))) short          bf16x8;
typedef __attribute__((ext_vector_type(4))) float          f32x4;
typedef __attribute__((ext_vector_type(16))) float         f32x16;
typedef __attribute__((ext_vector_type(4))) unsigned int   u32x4;
typedef __attribute__((ext_vector_type(4))) unsigned short us4;

static __device__ __forceinline__ unsigned short f2bf(float f) {
    unsigned int u = __float_as_uint(f);
    u += 0x7fffu + ((u >> 16) & 1u);      // round-to-nearest-even
    return (unsigned short)(u >> 16);
}

// pack two floats -> two bf16 in one dword (lo = a, hi = b)
static __device__ __forceinline__ unsigned int pk2bf(float a, float b) {
#if __has_builtin(__builtin_amdgcn_cvt_pk_bf16_f32)
    return __builtin_bit_cast(unsigned int,
                              __builtin_amdgcn_cvt_pk_bf16_f32(a, b));
#else
    unsigned int ua = __float_as_uint(a) + 0x8000u;   // round-half-up
    unsigned int ub = __float_as_uint(b) + 0x8000u;
    return __builtin_amdgcn_perm(ub, ua, 0x07060302u);
#endif
}

#if __has_builtin(__builtin_amdgcn_exp2f)
#define EXP2(x) __builtin_amdgcn_exp2f(x)
#else
#define EXP2(x) exp2f(x)
#endif

// async 16B global -> LDS (wave-uniform LDS base + lane*16)
static __device__ __forceinline__ void async_copy16(void* lds, const void* g) {
    __builtin_amdgcn_global_load_lds(
        (const __attribute__((address_space(1))) unsigned int*)g,
        (__attribute__((address_space(3))) unsigned int*)lds, 16, 0, 0);
}

// combine two unnormalized bf16 partials (packed pairs) with 1/l scale
static __device__ __forceinline__ unsigned int comb2(unsigned int x,
                                                     unsigned int y,
                                                     float inv) {
    float x0 = __uint_as_float(x << 16);
    float x1 = __uint_as_float(x & 0xffff0000u);
    float y0 = __uint_as_float(y << 16);
    float y1 = __uint_as_float(y & 0xffff0000u);
    return pk2bf((x0 + y0) * inv, (x1 + y1) * inv);
}

// T1 XCD-aware block swizzle: nwg % 8 == 0 required (bijective).
// HW dispatches flat ids round-robin across 8 XCDs; remap so each XCD
// computes a CONTIGUOUS tile range -> shared operand panels stay in its L2.
static __device__ __forceinline__ int xcd_swz(int flat, int nwg) {
    int cpx = nwg >> 3;
    return (flat & 7) * cpx + (flat >> 3);
}

// ---------------------------------------------------------------------------
// QKV GEMM epilogues through padded LDS (stride 136 shorts), then fully
// coalesced 16B global stores. Numerics identical to direct scatter.
// ---------------------------------------------------------------------------
#define CS_LD 136

// row-major output [h][tok][d] (Q scaled, K): Cs[row][col]
static __device__ __forceinline__ void epi_rowmajor(
        unsigned short* Cs, unsigned short* Out, const f32x4 (&acc)[4][4],
        float sc, int wr, int wc, int quad, int l15, int t, int bm, int bn) {
    __syncthreads();                       // all waves done reading As/Bs
    #pragma unroll
    for (int mt = 0; mt < 4; mt++)
        #pragma unroll
        for (int nt = 0; nt < 4; nt++) {
            int col = wc * 64 + nt * 16 + l15;
            int row = wr * 64 + mt * 16 + quad * 4;
            #pragma unroll
            for (int r = 0; r < 4; r++)
                Cs[(row + r) * CS_LD + col] = f2bf(acc[mt][nt][r] * sc);
        }
    __syncthreads();
    #pragma unroll
    for (int p = 0; p < 8; p++) {
        int idx = p * 2048 + t * 8;
        int rl = idx >> 7, cl = idx & 127;     // rl = tok, cl = n
        uint4 v = *(const uint4*)(Cs + rl * CS_LD + cl);
        int n = bn + cl;
        *(uint4*)(Out + (size_t)(n >> 6) * NTOK * HDIM
                      + (size_t)(bm + rl) * HDIM + (n & 63)) = v;
    }
}

// transposed output [h][d][tok] (V): Cs[col][row], us4 writes (4 consec tok)
static __device__ __forceinline__ void epi_transposed(
        unsigned short* Cs, unsigned short* Out, const f32x4 (&acc)[4][4],
        int wr, int wc, int quad, int l15, int t, int bm, int bn) {
    __syncthreads();
    #pragma unroll
    for (int mt = 0; mt < 4; mt++)
        #pragma unroll
        for (int nt = 0; nt < 4; nt++) {
            int col = wc * 64 + nt * 16 + l15;
            int row = wr * 64 + mt * 16 + quad * 4;
            us4 o = { f2bf(acc[mt][nt][0]), f2bf(acc[mt][nt][1]),
                      f2bf(acc[mt][nt][2]), f2bf(acc[mt][nt][3]) };
            *(us4*)(Cs + col * CS_LD + row) = o;
        }
    __syncthreads();
    #pragma unroll
    for (int p = 0; p < 8; p++) {
        int idx = p * 2048 + t * 8;
        int cl = idx >> 7, rl = idx & 127;     // cl = n (d), rl = tok
        uint4 v = *(const uint4*)(Cs + cl * CS_LD + rl);
        int n = bn + cl;
        *(uint4*)(Out + (size_t)(n >> 6) * HDIM * NTOK
                      + (size_t)(n & 63) * NTOK + (bm + rl)) = v;
    }
}

// ---------------------------------------------------------------------------
// cast + transpose weights: W [k][n] fp32 -> Wt [n][k] bf16. 64x64 LDS tiles.
// ---------------------------------------------------------------------------
__global__ __launch_bounds__(256)
void cast_wt_kernel(const float* __restrict__ Wq, const float* __restrict__ Wk,
                    const float* __restrict__ Wv, const float* __restrict__ Wo,
                    unsigned short* __restrict__ Tq, unsigned short* __restrict__ Tk,
                    unsigned short* __restrict__ Tv, unsigned short* __restrict__ To) {
    __shared__ float Ws[64][65];
    const float* W;
    unsigned short* T;
    switch (blockIdx.z) {
        case 0:  W = Wq; T = Tq; break;
        case 1:  W = Wk; T = Tk; break;
        case 2:  W = Wv; T = Tv; break;
        default: W = Wo; T = To; break;
    }
    const int k0 = blockIdx.x * 64, n0 = blockIdx.y * 64;
    const int t = threadIdx.x;
    #pragma unroll
    for (int i = 0; i < 4; i++) {
        int c  = i * 256 + t;
        int kk = c >> 4;
        int n4 = (c & 15) << 2;
        *(float4*)(&Ws[kk][n4]) =
            *(const float4*)(W + (size_t)(k0 + kk) * DMODEL + n0 + n4);
    }
    __syncthreads();
    #pragma unroll
    for (int i = 0; i < 4; i++) {
        int c  = i * 256 + t;
        int nn = c >> 4;
        int k4 = (c & 15) << 2;
        us4 o = { f2bf(Ws[k4 + 0][nn]), f2bf(Ws[k4 + 1][nn]),
                  f2bf(Ws[k4 + 2][nn]), f2bf(Ws[k4 + 3][nn]) };
        *(us4*)(T + (size_t)(n0 + nn) * KDIM + k0 + k4) = o;
    }
}

// ---------------------------------------------------------------------------
// cast activations fp32 -> bf16, flat row-major. grid (2048, 3).
// ---------------------------------------------------------------------------
__global__ __launch_bounds__(256)
void cast_in_kernel(const float* __restrict__ q, const float* __restrict__ k,
                    const float* __restrict__ v,
                    unsigned short* __restrict__ Qb,
                    unsigned short* __restrict__ Kb,
                    unsigned short* __restrict__ Vb) {
    const float* src;
    unsigned short* dst;
    switch (blockIdx.y) {
        case 0:  src = q; dst = Qb; break;
        case 1:  src = k; dst = Kb; break;
        default: src = v; dst = Vb; break;
    }
    size_t i = ((size_t)blockIdx.x * 256 + threadIdx.x) * 8;
    float4 f0 = *(const float4*)(src + i);
    float4 f1 = *(const float4*)(src + i + 4);
    uint2 o0 = { pk2bf(f0.x, f0.y), pk2bf(f0.z, f0.w) };
    uint2 o1 = { pk2bf(f1.x, f1.y), pk2bf(f1.z, f1.w) };
    *(uint2*)(dst + i)     = o0;
    *(uint2*)(dst + i + 4) = o1;
}

// ---------------------------------------------------------------------------
// QKV GEMM, pre-cast path: C = Ab(bf16)[4096x1024] x Bt(bf16)^T.
// mode 1: [h][tok][d] row-major (Q scaled, K). mode 2: [h][d][tok] (V).
// T1 XCD swizzle: each XCD gets 96 contiguous tiles (12 full A-bands local).
// ---------------------------------------------------------------------------
__global__ __launch_bounds__(256, 3)
void qkv_gemm_pre(const unsigned short* __restrict__ Qb,
                  const unsigned short* __restrict__ Kb,
                  const unsigned short* __restrict__ Vb,
                  const unsigned short* __restrict__ Btq,
                  const unsigned short* __restrict__ Btk,
                  const unsigned short* __restrict__ Btv,
                  unsigned short* __restrict__ Oq, unsigned short* __restrict__ Ok,
                  unsigned short* __restrict__ Ov) {
    __shared__ __align__(16) unsigned short Sm[17408];
    unsigned short* As = Sm;
    unsigned short* Bs = Sm + 8192;

    // XCD swizzle over the full 3D grid (x fastest): nwg = 8*32*3 = 768
    const int flat = blockIdx.x + 8 * (blockIdx.y + 32 * blockIdx.z);
    const int id   = xcd_swz(flat, 768);
    const int bx   = id & 7;
    const int by   = (id >> 3) & 31;
    const int bz   = id >> 8;

    const unsigned short* A;
    const unsigned short* Bt;
    unsigned short* Out;
    int mode;
    float sc;
    switch (bz) {
        case 0:  A = Qb; Bt = Btq; Out = Oq; mode = 1; sc = 0.18033688011112042f; break;
        case 1:  A = Kb; Bt = Btk; Out = Ok; mode = 1; sc = 1.0f; break;
        default: A = Vb; Bt = Btv; Out = Ov; mode = 2; sc = 1.0f; break;
    }

    const int t    = threadIdx.x;
    const int w    = t >> 6;
    const int lane = t & 63;
    const int quad = lane >> 4;
    const int l15  = lane & 15;
    const int wr   = w >> 1, wc = w & 1;
    const int bm   = by * 128, bn = bx * 128;

    f32x4 acc[4][4];
    #pragma unroll
    for (int i = 0; i < 4; i++)
        #pragma unroll
        for (int j = 0; j < 4; j++) acc[i][j] = (f32x4)(0.f);

    for (int k0 = 0; k0 < KDIM; k0 += 64) {
        __syncthreads();
        #pragma unroll
        for (int i = 0; i < 4; i++) {
            int cb = (i * 4 + w) * 64;
            int c  = cb + lane;
            int r  = c >> 3;
            int ko = (c & 7) * 8;
            async_copy16((void*)(Bs + cb * 8),
                         (const void*)(Bt + (size_t)(bn + r) * KDIM + k0 + ko));
            async_copy16((void*)(As + cb * 8),
                         (const void*)(A + (size_t)(bm + r) * KDIM + k0 + ko));
        }
        __syncthreads();
        #pragma unroll
        for (int kq = 0; kq < 2; kq++) {
            bf16x8 af[4], bf[4];
            #pragma unroll
            for (int mt = 0; mt < 4; mt++)
                af[mt] = *(bf16x8*)(As + (wr * 64 + mt * 16 + l15) * 64 + kq * 32 + quad * 8);
            #pragma unroll
            for (int nt = 0; nt < 4; nt++)
                bf[nt] = *(bf16x8*)(Bs + (wc * 64 + nt * 16 + l15) * 64 + kq * 32 + quad * 8);
            #pragma unroll
            for (int mt = 0; mt < 4; mt++)
                #pragma unroll
                for (int nt = 0; nt < 4; nt++)
                    acc[mt][nt] = __builtin_amdgcn_mfma_f32_16x16x32_bf16(
                        af[mt], bf[nt], acc[mt][nt], 0, 0, 0);
        }
    }

    if (mode == 1)
        epi_rowmajor(Sm, Out, acc, sc, wr, wc, quad, l15, t, bm, bn);
    else
        epi_transposed(Sm, Out, acc, wr, wc, quad, l15, t, bm, bn);
}

// ---------------------------------------------------------------------------
// QKV GEMM, fallback path (small ws): A fp32 cast in-register.
// ---------------------------------------------------------------------------
__global__ __launch_bounds__(256, 3)
void qkv_gemm(const float* __restrict__ Aq, const float* __restrict__ Ak,
              const float* __restrict__ Av,
              const unsigned short* __restrict__ Btq,
              const unsigned short* __restrict__ Btk,
              const unsigned short* __restrict__ Btv,
              unsigned short* __restrict__ Oq, unsigned short* __restrict__ Ok,
              unsigned short* __restrict__ Ov) {
    __shared__ __align__(16) unsigned short Sm[17408];
    unsigned short* As = Sm;
    unsigned short* Bs = Sm + 8192;

    const float* A;
    const unsigned short* Bt;
    unsigned short* Out;
    int mode;
    float sc;
    switch (blockIdx.z) {
        case 0:  A = Aq; Bt = Btq; Out = Oq; mode = 1; sc = 0.18033688011112042f; break;
        case 1:  A = Ak; Bt = Btk; Out = Ok; mode = 1; sc = 1.0f; break;
        default: A = Av; Bt = Btv; Out = Ov; mode = 2; sc = 1.0f; break;
    }

    const int t    = threadIdx.x;
    const int w    = t >> 6;
    const int lane = t & 63;
    const int quad = lane >> 4;
    const int l15  = lane & 15;
    const int wr   = w >> 1, wc = w & 1;
    const int bm   = blockIdx.y * 128, bn = blockIdx.x * 128;

    f32x4 acc[4][4];
    #pragma unroll
    for (int i = 0; i < 4; i++)
        #pragma unroll
        for (int j = 0; j < 4; j++) acc[i][j] = (f32x4)(0.f);

    for (int k0 = 0; k0 < KDIM; k0 += 64) {
        __syncthreads();
        #pragma unroll
        for (int i = 0; i < 4; i++) {
            int cb = (i * 4 + w) * 64;
            int c  = cb + lane;
            int r  = c >> 3;
            int ko = (c & 7) * 8;
            async_copy16((void*)(Bs + cb * 8),
                         (const void*)(Bt + (size_t)(bn + r) * KDIM + k0 + ko));
        }
        #pragma unroll
        for (int i = 0; i < 4; i++) {
            int c2 = i * 256 + t;
            int r  = c2 >> 3;
            int k8 = (c2 & 7) * 8;
            const float* src = A + (size_t)(bm + r) * KDIM + k0 + k8;
            float4 f0 = *(const float4*)(src);
            float4 f1 = *(const float4*)(src + 4);
            uint2 p0 = { pk2bf(f0.x, f0.y), pk2bf(f0.z, f0.w) };
            uint2 p1 = { pk2bf(f1.x, f1.y), pk2bf(f1.z, f1.w) };
            *(uint2*)(As + r * 64 + k8)     = p0;
            *(uint2*)(As + r * 64 + k8 + 4) = p1;
        }
        __syncthreads();
        #pragma unroll
        for (int kq = 0; kq < 2; kq++) {
            bf16x8 af[4], bf[4];
            #pragma unroll
            for (int mt = 0; mt < 4; mt++)
                af[mt] = *(bf16x8*)(As + (wr * 64 + mt * 16 + l15) * 64 + kq * 32 + quad * 8);
            #pragma unroll
            for (int nt = 0; nt < 4; nt++)
                bf[nt] = *(bf16x8*)(Bs + (wc * 64 + nt * 16 + l15) * 64 + kq * 32 + quad * 8);
            #pragma unroll
            for (int mt = 0; mt < 4; mt++)
                #pragma unroll
                for (int nt = 0; nt < 4; nt++)
                    acc[mt][nt] = __builtin_amdgcn_mfma_f32_16x16x32_bf16(
                        af[mt], bf[nt], acc[mt][nt], 0, 0, 0);
        }
    }

    if (mode == 1)
        epi_rowmajor(Sm, Out, acc, sc, wr, wc, quad, l15, t, bm, bn);
    else
        epi_transposed(Sm, Out, acc, wr, wc, quad, l15, t, bm, bn);
}

// ---------------------------------------------------------------------------
// Output GEMM (fallback): out(fp32) = ctx(bf16) x WoT(bf16)^T. 64x128 tile.
// ---------------------------------------------------------------------------
__global__ __launch_bounds__(256, 3)
void out_gemm(const unsigned short* __restrict__ A,
              const unsigned short* __restrict__ Bt,
              float* __restrict__ Out) {
    __shared__ unsigned short As[64 * 64];
    __shared__ unsigned short Bs[128 * 64];

    const int t    = threadIdx.x;
    const int w    = t >> 6;
    const int lane = t & 63;
    const int quad = lane >> 4;
    const int l15  = lane & 15;
    const int wr   = w >> 1, wc = w & 1;
    const int bm   = blockIdx.y * 64, bn = blockIdx.x * 128;

    f32x4 acc[2][4];
    #pragma unroll
    for (int i = 0; i < 2; i++)
        #pragma unroll
        for (int j = 0; j < 4; j++) acc[i][j] = (f32x4)(0.f);

    for (int k0 = 0; k0 < KDIM; k0 += 64) {
        __syncthreads();
        #pragma unroll
        for (int i = 0; i < 4; i++) {
            int cb = (i * 4 + w) * 64;
            int c  = cb + lane;
            int r  = c >> 3;
            int ko = (c & 7) * 8;
            async_copy16((void*)(Bs + cb * 8),
                         (const void*)(Bt + (size_t)(bn + r) * KDIM + k0 + ko));
        }
        #pragma unroll
        for (int i = 0; i < 2; i++) {
            int cb = (i * 4 + w) * 64;
            int c  = cb + lane;
            int r  = c >> 3;
            int ko = (c & 7) * 8;
            async_copy16((void*)(As + cb * 8),
                         (const void*)(A + (size_t)(bm + r) * KDIM + k0 + ko));
        }
        __syncthreads();
        #pragma unroll
        for (int kq = 0; kq < 2; kq++) {
            bf16x8 af[2], bf[4];
            #pragma unroll
            for (int mt = 0; mt < 2; mt++)
                af[mt] = *(bf16x8*)(As + (wr * 32 + mt * 16 + l15) * 64 + kq * 32 + quad * 8);
            #pragma unroll
            for (int nt = 0; nt < 4; nt++)
                bf[nt] = *(bf16x8*)(Bs + (wc * 64 + nt * 16 + l15) * 64 + kq * 32 + quad * 8);
            #pragma unroll
            for (int mt = 0; mt < 2; mt++)
                #pragma unroll
                for (int nt = 0; nt < 4; nt++)
                    acc[mt][nt] = __builtin_amdgcn_mfma_f32_16x16x32_bf16(
                        af[mt], bf[nt], acc[mt][nt], 0, 0, 0);
        }
    }

    #pragma unroll
    for (int mt = 0; mt < 2; mt++) {
        #pragma unroll
        for (int nt = 0; nt < 4; nt++) {
            int col  = bn + wc * 64 + nt * 16 + l15;
            int row0 = bm + wr * 32 + mt * 16 + quad * 4;
            #pragma unroll
            for (int r = 0; r < 4; r++)
                Out[(size_t)(row0 + r) * DMODEL + col] = acc[mt][nt][r];
        }
    }
}

// ---------------------------------------------------------------------------
// Output GEMM + fused split-K combine: A-tile = (POa + POb) / (la + lb).
// T1 XCD swizzle: each XCD gets 64 contiguous tiles (8 PO bands local).
// ---------------------------------------------------------------------------
__global__ __launch_bounds__(256, 3)
void out_gemm_comb(const unsigned short* __restrict__ POa,
                   const float* __restrict__ lbuf,
                   const unsigned short* __restrict__ Bt,
                   float* __restrict__ Out) {
    __shared__ unsigned short As[64 * 64];
    __shared__ unsigned short Bs[128 * 64];

    const unsigned short* POb = POa + (size_t)NTOK * DMODEL;

    // XCD swizzle: nwg = 8*64 = 512
    const int flat = blockIdx.x + 8 * blockIdx.y;
    const int id   = xcd_swz(flat, 512);
    const int bx   = id & 7;
    const int by   = id >> 3;

    const int t    = threadIdx.x;
    const int w    = t >> 6;
    const int lane = t & 63;
    const int quad = lane >> 4;
    const int l15  = lane & 15;
    const int wr   = w >> 1, wc = w & 1;
    const int bm   = by * 64, bn = bx * 128;

    f32x4 acc[2][4];
    #pragma unroll
    for (int i = 0; i < 2; i++)
        #pragma unroll
        for (int j = 0; j < 4; j++) acc[i][j] = (f32x4)(0.f);

    for (int k0 = 0; k0 < KDIM; k0 += 64) {
        __syncthreads();
        #pragma unroll
        for (int i = 0; i < 4; i++) {
            int cb = (i * 4 + w) * 64;
            int c  = cb + lane;
            int r  = c >> 3;
            int ko = (c & 7) * 8;
            async_copy16((void*)(Bs + cb * 8),
                         (const void*)(Bt + (size_t)(bn + r) * KDIM + k0 + ko));
        }
        // A-tile: load both PO halves, combine with 1/(la+lb), ds_write bf16
        #pragma unroll
        for (int i = 0; i < 2; i++) {
            int c   = i * 256 + t;        // 0..511
            int r   = c >> 3;             // row 0..63
            int k8  = (c & 7) * 8;        // col offset 0..56
            size_t row = (size_t)(bm + r);
            int col = k0 + k8;
            int hh  = col >> 6;
            uint4 a = *(const uint4*)(POa + row * DMODEL + col);
            uint4 b = *(const uint4*)(POb + row * DMODEL + col);
            float la = lbuf[(size_t)hh * NTOK + row];
            float lb = lbuf[(size_t)NHEADS * NTOK + (size_t)hh * NTOK + row];
            float inv = 1.f / (la + lb);
            uint4 o = { comb2(a.x, b.x, inv), comb2(a.y, b.y, inv),
                        comb2(a.z, b.z, inv), comb2(a.w, b.w, inv) };
            *(uint4*)(As + r * 64 + k8) = o;
        }
        __syncthreads();
        #pragma unroll
        for (int kq = 0; kq < 2; kq++) {
            bf16x8 af[2], bf[4];
            #pragma unroll
            for (int mt = 0; mt < 2; mt++)
                af[mt] = *(bf16x8*)(As + (wr * 32 + mt * 16 + l15) * 64 + kq * 32 + quad * 8);
            #pragma unroll
            for (int nt = 0; nt < 4; nt++)
                bf[nt] = *(bf16x8*)(Bs + (wc * 64 + nt * 16 + l15) * 64 + kq * 32 + quad * 8);
            #pragma unroll
            for (int mt = 0; mt < 2; mt++)
                #pragma unroll
                for (int nt = 0; nt < 4; nt++)
                    acc[mt][nt] = __builtin_amdgcn_mfma_f32_16x16x32_bf16(
                        af[mt], bf[nt], acc[mt][nt], 0, 0, 0);
        }
    }

    #pragma unroll
    for (int mt = 0; mt < 2; mt++) {
        #pragma unroll
        for (int nt = 0; nt < 4; nt++) {
            int col  = bn + wc * 64 + nt * 16 + l15;
            int row0 = bm + wr * 32 + mt * 16 + quad * 4;
            #pragma unroll
            for (int r = 0; r < 4; r++)
                Out[(size_t)(row0 + r) * DMODEL + col] = acc[mt][nt][r];
        }
    }
}

// ---------------------------------------------------------------------------
// Flash attention SPLIT-K, 32x32x16 MFMA + in-register P (validated).
// T1 XCD swizzle: each XCD gets 128 contiguous tiles = all 32 qt-blocks for
// 4 (h,half) pairs -> 2 MB K/V resident in its L2, re-read 32x locally
// (was: 32 qt-blocks round-robin on 8 XCDs -> ~512 MB L3 traffic).
// ---------------------------------------------------------------------------
__global__ __launch_bounds__(256, 4)
void attn_split(const unsigned short* __restrict__ Q,
                const unsigned short* __restrict__ K,
                const unsigned short* __restrict__ Vt,
                unsigned short* __restrict__ PO,   // [half][row][h*64+d] bf16
                float* __restrict__ lbuf) {        // [half][h][row] fp32
    __shared__ __align__(16) unsigned short Ks[2 * 4096]; // [buf][key 64][d 64] XOR-chunked
    __shared__ __align__(16) unsigned short Vs[2 * 4096]; // [buf][d 64][key 64] XOR-chunked

    // XCD swizzle: nwg = 32*16*2 = 1024
    const int flat = blockIdx.x + 32 * (blockIdx.y + 16 * blockIdx.z);
    const int id   = xcd_swz(flat, 1024);
    const int qt   = id & 31;          // 128 q rows
    const int h    = (id >> 5) & 15;
    const int half = id >> 9;          // keys [half*2048, half*2048+2048)

    const int t    = threadIdx.x;
    const int w    = t >> 6;
    const int lane = t & 63;
    const int r    = lane & 31;        // q-col (B) / key- or d-row (A)
    const int hi   = lane >> 5;
    const int xh   = (r & 7) ^ hi;     // XOR-chunk key for frag reads

    // Q fragments (B operand): lane holds Q[qrow][ds*16 + 8*hi + j]
    const unsigned short* Qg =
        Q + ((size_t)h * NTOK + qt * 128 + w * 32 + r) * HDIM + hi * 8;
    bf16x8 qf[4];
    #pragma unroll
    for (int ds = 0; ds < 4; ds++)
        qf[ds] = *(const bf16x8*)(Qg + ds * 16);

    const unsigned short* Kg = K  + ((size_t)h * NTOK + half * 2048) * HDIM;
    const unsigned short* Vg = Vt + (size_t)h * HDIM * NTOK + half * 2048;

    // staging source (hoisted): thread covers row rr, XOR-swizzled chunk
    const int rr = t >> 3;
    const int oo = ((t & 7) ^ (rr & 7)) * 8;
    const unsigned short* kbase = Kg + (size_t)rr * HDIM + oo;
    const unsigned short* vbase = Vg + (size_t)rr * NTOK + oo;
    unsigned short* ksd = Ks + w * 512;   // wave-uniform LDS dest
    unsigned short* vsd = Vs + w * 512;

    auto stage = [&](int kt, int b) {
        const unsigned short* kp = kbase + (size_t)kt * 64 * HDIM;
        const unsigned short* vp = vbase + kt * 64;
        async_copy16((void*)(ksd + b * 4096),        (const void*)kp);
        async_copy16((void*)(ksd + b * 4096 + 2048), (const void*)(kp + 32 * HDIM));
        async_copy16((void*)(vsd + b * 4096),        (const void*)vp);
        async_copy16((void*)(vsd + b * 4096 + 2048), (const void*)(vp + (size_t)32 * NTOK));
    };

    f32x16 O0 = (f32x16)(0.f), O1 = (f32x16)(0.f);
    float l0 = 0.f, l1 = 0.f, l2 = 0.f, l3 = 0.f;

    stage(0, 0);

    for (int kt = 0; kt < 32; kt++) {
        const int cur = kt & 1;
        __syncthreads();                    // drains vmcnt for buf[cur]
        if (kt + 1 < 32) stage(kt + 1, cur ^ 1);

        const unsigned short* Kb = Ks + cur * 4096 + r * 64;
        const unsigned short* Vb = Vs + cur * 4096 + r * 64;

        // ---- S^T = K Q^T : two 32-key blocks, K-dim 64 = 4 slices ----
        f32x16 S0 = (f32x16)(0.f), S1 = (f32x16)(0.f);
        #pragma unroll
        for (int ds = 0; ds < 4; ds++) {
            int c = ((2 * ds) ^ xh) * 8;
            bf16x8 k0 = *(const bf16x8*)(Kb + c);
            bf16x8 k1 = *(const bf16x8*)(Kb + 2048 + c);
            S0 = __builtin_amdgcn_mfma_f32_32x32x16_bf16(k0, qf[ds], S0, 0, 0, 0);
            S1 = __builtin_amdgcn_mfma_f32_32x32x16_bf16(k1, qf[ds], S1, 0, 0, 0);
        }

        // ---- per key-block: exp2 -> pack -> permlane swap -> PV ----
        #pragma unroll
        for (int kb = 0; kb < 2; kb++) {
            const f32x16 S = kb ? S1 : S0;
            float p[16];
            #pragma unroll
            for (int i = 0; i < 16; i++) p[i] = EXP2(S[i]);
            // l accumulation: 4 independent chains
            #pragma unroll
            for (int i = 0; i < 4; i++) {
                l0 += p[i * 4 + 0];
                l1 += p[i * 4 + 1];
                l2 += p[i * 4 + 2];
                l3 += p[i * 4 + 3];
            }
            #pragma unroll
            for (int g = 0; g < 2; g++) {   // 16-key group within block
                unsigned int w0 = pk2bf(p[g * 8 + 0], p[g * 8 + 1]);
                unsigned int w2 = pk2bf(p[g * 8 + 4], p[g * 8 + 5]);
                unsigned int w1 = pk2bf(p[g * 8 + 2], p[g * 8 + 3]);
                unsigned int w3 = pk2bf(p[g * 8 + 6], p[g * 8 + 7]);
                asm volatile("v_permlane32_swap_b32 %0, %1" : "+v"(w0), "+v"(w2));
                asm volatile("v_permlane32_swap_b32 %0, %1" : "+v"(w1), "+v"(w3));
                u32x4 pw = { w0, w1, w2, w3 };
                bf16x8 pf = __builtin_bit_cast(bf16x8, pw);
                int kg = kb * 2 + g;
                int c  = ((2 * kg) ^ xh) * 8;
                bf16x8 v0 = *(const bf16x8*)(Vb + c);
                bf16x8 v1 = *(const bf16x8*)(Vb + 2048 + c);
                O0 = __builtin_amdgcn_mfma_f32_32x32x16_bf16(v0, pf, O0, 0, 0, 0);
                O1 = __builtin_amdgcn_mfma_f32_32x32x16_bf16(v1, pf, O1, 0, 0, 0);
            }
        }
    }

    // ---- epilogue: unnormalized partial O (bf16) + l (fp32) ----
    float lt  = (l0 + l1) + (l2 + l3);
    float ltot = lt + __shfl_xor(lt, 32, 64);

    unsigned short* POh = PO + (size_t)half * NTOK * DMODEL;
    size_t row = (size_t)qt * 128 + w * 32 + r;
    unsigned short* dst = POh + row * DMODEL + h * HDIM;
    #pragma unroll
    for (int db = 0; db < 2; db++) {
        const f32x16 O = db ? O1 : O0;
        #pragma unroll
        for (int g = 0; g < 4; g++) {
            int d = db * 32 + g * 8 + hi * 4;   // C row = (reg&3)+8*(reg>>2)+4*hi
            uint2 o = { pk2bf(O[g * 4 + 0], O[g * 4 + 1]),
                        pk2bf(O[g * 4 + 2], O[g * 4 + 3]) };
            *(uint2*)(dst + d) = o;
        }
    }
    if (hi == 0)
        lbuf[((size_t)half * NHEADS + h) * NTOK + row] = ltot;
}

// ---------------------------------------------------------------------------
// Fallback single-pass attention (small ws), Ps-based (validated).
// ---------------------------------------------------------------------------
__global__ __launch_bounds__(256)
void attn_mfma(const unsigned short* __restrict__ Q,
               const unsigned short* __restrict__ K,
               const unsigned short* __restrict__ Vt,
               unsigned short* __restrict__ ctx) {
    __shared__ __align__(16) unsigned short Ks[2 * 4096];
    __shared__ __align__(16) unsigned short Vs[2 * 4096];
    __shared__ __align__(16) unsigned short Ps[4][32][72];

    const int h    = blockIdx.y;
    const int qt   = blockIdx.x;
    const int t    = threadIdx.x;
    const int w    = t >> 6;
    const int lane = t & 63;
    const int quad = lane >> 4;
    const int l15  = lane & 15;

    const unsigned short* Qg =
        Q + ((size_t)h * NTOK + qt * 128 + w * 32 + l15) * HDIM;
    bf16x8 qf[2][2];
    qf[0][0] = *(const bf16x8*)(Qg + quad * 8);
    qf[0][1] = *(const bf16x8*)(Qg + 32 + quad * 8);
    qf[1][0] = *(const bf16x8*)(Qg + 16 * HDIM + quad * 8);
    qf[1][1] = *(const bf16x8*)(Qg + 16 * HDIM + 32 + quad * 8);

    const unsigned short* Kg = K  + (size_t)h * NTOK * HDIM;
    const unsigned short* Vg = Vt + (size_t)h * HDIM * NTOK;

    const int rr = t >> 3;
    const int oo = ((t & 7) ^ (rr & 7)) * 8;
    const unsigned short* kbase = Kg + (size_t)rr * HDIM + oo;
    const unsigned short* vbase = Vg + (size_t)rr * NTOK + oo;
    unsigned short* ksd = Ks + w * 512;
    unsigned short* vsd = Vs + w * 512;

    auto stage = [&](int kt, int b) {
        const unsigned short* kp = kbase + (size_t)kt * 64 * HDIM;
        const unsigned short* vp = vbase + kt * 64;
        async_copy16((void*)(ksd + b * 4096),        (const void*)kp);
        async_copy16((void*)(ksd + b * 4096 + 2048), (const void*)(kp + 32 * HDIM));
        async_copy16((void*)(vsd + b * 4096),        (const void*)vp);
        async_copy16((void*)(vsd + b * 4096 + 2048), (const void*)(vp + (size_t)32 * NTOK));
    };

    const int xb = l15 & 7;
    const int a0 = l15 * 64 + ((quad    ) ^ xb) * 8;
    const int a1 = l15 * 64 + ((quad + 4) ^ xb) * 8;

    const bf16x8 ones = { 16256, 16256, 16256, 16256,
                          16256, 16256, 16256, 16256 };

    f32x4 O[2][4];
    f32x4 lacc[2];
    #pragma unroll
    for (int tl = 0; tl < 2; tl++) {
        lacc[tl] = (f32x4)(0.f);
        #pragma unroll
        for (int dt = 0; dt < 4; dt++) O[tl][dt] = (f32x4)(0.f);
    }

    stage(0, 0);

    for (int kt = 0; kt < NTOK / 64; kt++) {
        const int cur = kt & 1;
        __syncthreads();
        if (kt + 1 < NTOK / 64) stage(kt + 1, cur ^ 1);

        f32x4 s[2][4];
        #pragma unroll
        for (int kc = 0; kc < 4; kc++) {
            bf16x8 kf0 = *(bf16x8*)(Ks + cur * 4096 + kc * 1024 + a0);
            bf16x8 kf1 = *(bf16x8*)(Ks + cur * 4096 + kc * 1024 + a1);
            #pragma unroll
            for (int tl = 0; tl < 2; tl++) {
                f32x4 acc = (f32x4)(0.f);
                acc = __builtin_amdgcn_mfma_f32_16x16x32_bf16(kf0, qf[tl][0], acc, 0, 0, 0);
                acc = __builtin_amdgcn_mfma_f32_16x16x32_bf16(kf1, qf[tl][1], acc, 0, 0, 0);
                s[tl][kc] = acc;
            }
        }

        bf16x8 vf[4][2];
        #pragma unroll
        for (int dt = 0; dt < 4; dt++) {
            vf[dt][0] = *(bf16x8*)(Vs + cur * 4096 + dt * 1024 + a0);
            vf[dt][1] = *(bf16x8*)(Vs + cur * 4096 + dt * 1024 + a1);
        }

        #pragma unroll
        for (int tl = 0; tl < 2; tl++) {
            #pragma unroll
            for (int kc = 0; kc < 4; kc++) {
                float e0 = EXP2(s[tl][kc][0]);
                float e1 = EXP2(s[tl][kc][1]);
                float e2 = EXP2(s[tl][kc][2]);
                float e3 = EXP2(s[tl][kc][3]);
                uint2 p = { pk2bf(e0, e1), pk2bf(e2, e3) };
                *(uint2*)(&Ps[w][tl * 16 + l15][kc * 16 + quad * 4]) = p;
            }
            asm volatile("s_waitcnt lgkmcnt(0)" ::: "memory");

            bf16x8 pf0 = *(bf16x8*)(&Ps[w][tl * 16 + l15][quad * 8]);
            bf16x8 pf1 = *(bf16x8*)(&Ps[w][tl * 16 + l15][32 + quad * 8]);
            lacc[tl] = __builtin_amdgcn_mfma_f32_16x16x32_bf16(ones, pf0, lacc[tl], 0, 0, 0);
            lacc[tl] = __builtin_amdgcn_mfma_f32_16x16x32_bf16(ones, pf1, lacc[tl], 0, 0, 0);
            #pragma unroll
            for (int dt = 0; dt < 4; dt++) {
                O[tl][dt] = __builtin_amdgcn_mfma_f32_16x16x32_bf16(vf[dt][0], pf0, O[tl][dt], 0, 0, 0);
                O[tl][dt] = __builtin_amdgcn_mfma_f32_16x16x32_bf16(vf[dt][1], pf1, O[tl][dt], 0, 0, 0);
            }
        }
    }

    #pragma unroll
    for (int tl = 0; tl < 2; tl++) {
        float inv = 1.f / lacc[tl][0];
        size_t row = (size_t)qt * 128 + w * 32 + tl * 16 + l15;
        #pragma unroll
        for (int dt = 0; dt < 4; dt++) {
            uint2 o = { pk2bf(O[tl][dt][0] * inv, O[tl][dt][1] * inv),
                        pk2bf(O[tl][dt][2] * inv, O[tl][dt][3] * inv) };
            *(uint2*)(ctx + row * DMODEL + h * HDIM + dt * 16 + quad * 4) = o;
        }
    }
}

// ---------------------------------------------------------------------------
extern "C" void kernel_launch(void* const* d_in, const int* in_sizes, int n_in,
                              void* d_out, int out_size, void* d_ws, size_t ws_size,
                              hipStream_t stream) {
    const float* q  = (const float*)d_in[0];
    const float* k  = (const float*)d_in[1];
    const float* v  = (const float*)d_in[2];
    const float* Wq = (const float*)d_in[3];
    const float* Wk = (const float*)d_in[4];
    const float* Wv = (const float*)d_in[5];
    const float* Wo = (const float*)d_in[6];
    float* out = (float*)d_out;

    // ws: weights 8MB | Qh,Kh,Vth 24MB | ctx 8MB | scratch 24MB
    // scratch = Qb/Kb/Vb during projections, then PO(16MB)+lbuf(0.5MB) in attn.
    unsigned short* WqT = (unsigned short*)d_ws;
    unsigned short* WkT = WqT + (size_t)DMODEL * KDIM;
    unsigned short* WvT = WkT + (size_t)DMODEL * KDIM;
    unsigned short* WoT = WvT + (size_t)DMODEL * KDIM;
    unsigned short* Qh  = WoT + (size_t)DMODEL * KDIM;   // [h][tok][d]
    unsigned short* Kh  = Qh  + (size_t)NTOK * DMODEL;   // [h][tok][d]
    unsigned short* Vth = Kh  + (size_t)NTOK * DMODEL;   // [h][d][tok]
    unsigned short* ctx = Vth + (size_t)NTOK * DMODEL;
    unsigned short* Qb  = ctx + (size_t)NTOK * DMODEL;
    unsigned short* Kb  = Qb  + (size_t)NTOK * DMODEL;
    unsigned short* Vb  = Kb  + (size_t)NTOK * DMODEL;
    unsigned short* PO  = Qb;                                // overlay (Qb dead)
    float*          lb  = (float*)(PO + (size_t)2 * NTOK * DMODEL);

    const bool bigws = ws_size >= (size_t)67108864;   // 64 MB

    cast_wt_kernel<<<dim3(16, 16, 4), 256, 0, stream>>>(Wq, Wk, Wv, Wo,
                                                        WqT, WkT, WvT, WoT);
    if (bigws) {
        cast_in_kernel<<<dim3(2048, 3), 256, 0, stream>>>(q, k, v, Qb, Kb, Vb);
        qkv_gemm_pre<<<dim3(DMODEL / 128, NTOK / 128, 3), 256, 0, stream>>>(
            Qb, Kb, Vb, WqT, WkT, WvT, Qh, Kh, Vth);
        attn_split<<<dim3(NTOK / 128, NHEADS, 2), 256, 0, stream>>>(
            Qh, Kh, Vth, PO, lb);
        out_gemm_comb<<<dim3(DMODEL / 128, NTOK / 64), 256, 0, stream>>>(
            PO, lb, WoT, out);
    } else {
        qkv_gemm<<<dim3(DMODEL / 128, NTOK / 128, 3), 256, 0, stream>>>(
            q, k, v, WqT, WkT, WvT, Qh, Kh, Vth);
        attn_mfma<<<dim3(NTOK / 128, NHEADS), 256, 0, stream>>>(Qh, Kh, Vth, ctx);
        out_gemm<<<dim3(DMODEL / 128, NTOK / 64), 256, 0, stream>>>(ctx, WoT, out);
    }
}